// Round 17
// baseline (250.252 us; speedup 1.0000x reference)
//
#include <hip/hip_runtime.h>
#include <hip/hip_bf16.h>

// Causal attention block: out = softmax(mask(QK^T/sqrt(D))) V projections.
// B=2, T=2048, C=2048, H=16, D=128. fp32 I/O, bf16 MFMA compute internally.
//
// Pipeline:
//   1. cvt_all: x + 4 weights f32->bf16 in ONE launch
//   2. gemm_bt<0> x2 (Q,K -> [B,H,T,D]), gemm_bt<1> (V -> [B,H,D,T])
//   3. attn_fwd: QBLK=128, 4 waves x 32 q-rows (i=0,1): K/V reads feed two
//        MFMAs (LDS-read-bound model). 64KB LDS = K dbuf 32K + V single 16K
//        (JIT-staged, consumed post-softmax) + P 16K -> 2 blocks/CU.
//        exp2 softmax, defer-max, ones-MFMA denominator, bh->XCD map.
//   4. gemm_bt<2>: out = attn@wo.T -> fp32 d_out
//
// GEMM: 256x128 tile, BK=64, TRIPLE-buffered swizzled LDS (144KB), ONE
// barrier + vmcnt(6) per K-tile (R16-verified), XCD swizzle, setprio.

#define BB 2
#define TT 2048
#define CC 2048
#define HH 16
#define DD 128
#define MM (BB*TT)   // 4096
#define NQB (TT/128) // 16 attn q-blocks (128 rows)
#define GNT (CC/64)  // 32 K-tiles in GEMM

typedef __bf16 bf16x8 __attribute__((ext_vector_type(8)));
typedef __bf16 bf16x4 __attribute__((ext_vector_type(4)));
typedef float  f32x4  __attribute__((ext_vector_type(4)));

#define MFMA16(a, b, c) __builtin_amdgcn_mfma_f32_16x16x32_bf16((a), (b), (c), 0, 0, 0)

__device__ __forceinline__ void g2lds16(const void* g, void* l) {
    __builtin_amdgcn_global_load_lds(
        (const __attribute__((address_space(1))) void*)g,
        (__attribute__((address_space(3))) void*)l,
        16, 0, 0);
}

// ---------------------------------------------------------------- convert
__global__ __launch_bounds__(256) void cvt_all(
    const float* __restrict__ x,  const float* __restrict__ wq,
    const float* __restrict__ wk, const float* __restrict__ wv,
    const float* __restrict__ wo, __bf16* __restrict__ out_base)
{
    const int idx = blockIdx.x * 256 + threadIdx.x;   // < 6291456
    const float* in; int off;
    if (idx < (1 << 21)) { in = x; off = idx; }
    else {
        const int r = idx - (1 << 21);
        const int k = r >> 20;
        in  = (k == 0) ? wq : (k == 1) ? wk : (k == 2) ? wv : wo;
        off = r & ((1 << 20) - 1);
    }
    const float4 v = ((const float4*)in)[off];
    bf16x4 o;
    o.x = (__bf16)v.x; o.y = (__bf16)v.y;
    o.z = (__bf16)v.z; o.w = (__bf16)v.w;
    ((bf16x4*)out_base)[idx] = o;
}

// ---------------------------------------------------------------- GEMM (B^T)
// (R16-verified: ~31us each; ONE barrier + vmcnt(6) per K-tile)
template<int MODE>
__global__ __launch_bounds__(512, 2) void gemm_bt(
    const __bf16* __restrict__ A, const __bf16* __restrict__ Wt,
    void* __restrict__ out)
{
    __shared__ __align__(16) __bf16 As[3][256*64];      // 96 KB, 128B rows
    __shared__ __align__(16) __bf16 Bs[3][2][128*32];   // 48 KB, 64B rows, k-sliced

    const int tid = threadIdx.x;
    const int w   = tid >> 6, lane = tid & 63;
    const int wm  = w >> 1,  wn  = w & 1;
    const int lo  = lane & 15, hi = lane >> 4;
    const int xr  = (lo & 7) << 4;
    const int xb2 = ((lo >> 1) & 3) << 4;

    const int bid   = blockIdx.y * gridDim.x + blockIdx.x;
    const int xcd   = bid & 7, loc = bid >> 3;
    const int n0    = (2*xcd + (loc & 1)) * 128;
    const int m0    = (loc >> 1) * 256;

    const int ar   = tid >> 3, as_ = tid & 7;
    const int acol = ((as_ ^ (ar & 7)) << 3);
    const int br   = tid >> 2, bs_ = tid & 3;
    const int bcol = ((bs_ ^ ((br >> 1) & 3)) << 3);

    auto stageA3a = [&](int buf, int kt) {               // A loads j=0,1,2
        #pragma unroll
        for (int j = 0; j < 3; ++j)
            g2lds16(A + (size_t)(m0 + j*64 + ar)*CC + kt*64 + acol,
                    (char*)&As[buf][0] + j*8192 + w*1024);
    };
    auto stageA3b = [&](int buf, int kt) {               // A j=3 + B kh=0,1
        g2lds16(A + (size_t)(m0 + 3*64 + ar)*CC + kt*64 + acol,
                (char*)&As[buf][0] + 3*8192 + w*1024);
        #pragma unroll
        for (int kh = 0; kh < 2; ++kh)
            g2lds16(Wt + (size_t)(n0 + br)*CC + kt*64 + kh*32 + bcol,
                    (char*)&Bs[buf][kh][0] + w*1024);
    };
    auto rdA = [&](bf16x8* af, int buf, int ks) {
        const char* base = (const char*)&As[buf][0];
        #pragma unroll
        for (int mf = 0; mf < 4; ++mf) {
            const int r = wm*64 + mf*16 + lo;
            af[mf] = *(const bf16x8*)(base + r*128 + ((ks*64 + hi*16) ^ xr));
        }
    };
    auto rdB = [&](bf16x8* bv, int buf, int ks) {
        const char* base = (const char*)&Bs[buf][ks][0];
        #pragma unroll
        for (int nf = 0; nf < 4; ++nf) {
            const int n = wn*64 + nf*16 + lo;
            bv[nf] = *(const bf16x8*)(base + n*64 + ((hi*16) ^ xb2));
        }
    };

    f32x4 acc[4][4] = {};

    stageA3a(0, 0); stageA3b(0, 0);
    stageA3a(1, 1); stageA3b(1, 1);
    asm volatile("s_waitcnt vmcnt(6)" ::: "memory");
    __builtin_amdgcn_s_barrier();

    int rb = 0;   // read buffer = t%3
    #pragma unroll 1
    for (int t = 0; t < GNT - 2; ++t) {
        const int sb = (rb == 0) ? 2 : rb - 1;   // (t+2)%3
        {
            bf16x8 af[4], bv[4];
            rdA(af, rb, 0); rdB(bv, rb, 0);
            stageA3a(sb, t + 2);
            __builtin_amdgcn_s_setprio(1);
            #pragma unroll
            for (int mf = 0; mf < 4; ++mf)
                #pragma unroll
                for (int nf = 0; nf < 4; ++nf)
                    acc[mf][nf] = MFMA16(af[mf], bv[nf], acc[mf][nf]);
            __builtin_amdgcn_s_setprio(0);
        }
        {
            bf16x8 af[4], bv[4];
            rdA(af, rb, 1); rdB(bv, rb, 1);
            stageA3b(sb, t + 2);
            __builtin_amdgcn_s_setprio(1);
            #pragma unroll
            for (int mf = 0; mf < 4; ++mf)
                #pragma unroll
                for (int nf = 0; nf < 4; ++nf)
                    acc[mf][nf] = MFMA16(af[mf], bv[nf], acc[mf][nf]);
            __builtin_amdgcn_s_setprio(0);
            asm volatile("s_waitcnt vmcnt(6)" ::: "memory"); // t+1 landed
            __builtin_amdgcn_s_barrier();                    // tile boundary
        }
        rb = (rb == 2) ? 0 : rb + 1;
    }
    {   // peeled t = GNT-2 (no staging)
        bf16x8 af[4], bv[4];
        rdA(af, rb, 0); rdB(bv, rb, 0);
        #pragma unroll
        for (int mf = 0; mf < 4; ++mf)
            #pragma unroll
            for (int nf = 0; nf < 4; ++nf)
                acc[mf][nf] = MFMA16(af[mf], bv[nf], acc[mf][nf]);
        rdA(af, rb, 1); rdB(bv, rb, 1);
        #pragma unroll
        for (int mf = 0; mf < 4; ++mf)
            #pragma unroll
            for (int nf = 0; nf < 4; ++nf)
                acc[mf][nf] = MFMA16(af[mf], bv[nf], acc[mf][nf]);
        asm volatile("s_waitcnt vmcnt(0)" ::: "memory");     // last tile landed
        __builtin_amdgcn_s_barrier();
        rb = (rb == 2) ? 0 : rb + 1;
    }
    {   // peeled t = GNT-1 (compute only)
        bf16x8 af[4], bv[4];
        rdA(af, rb, 0); rdB(bv, rb, 0);
        #pragma unroll
        for (int mf = 0; mf < 4; ++mf)
            #pragma unroll
            for (int nf = 0; nf < 4; ++nf)
                acc[mf][nf] = MFMA16(af[mf], bv[nf], acc[mf][nf]);
        rdA(af, rb, 1); rdB(bv, rb, 1);
        #pragma unroll
        for (int mf = 0; mf < 4; ++mf)
            #pragma unroll
            for (int nf = 0; nf < 4; ++nf)
                acc[mf][nf] = MFMA16(af[mf], bv[nf], acc[mf][nf]);
    }

    #pragma unroll
    for (int mf = 0; mf < 4; ++mf) {
        #pragma unroll
        for (int nf = 0; nf < 4; ++nf) {
            #pragma unroll
            for (int r = 0; r < 4; ++r) {
                const int row = m0 + wm*64 + mf*16 + hi*4 + r;   // m
                const int col = n0 + wn*64 + nf*16 + lo;         // n
                const float v = acc[mf][nf][r];
                if (MODE == 0) {
                    const int b = row >> 11, t = row & (TT-1);
                    const int h = col >> 7,  d = col & (DD-1);
                    ((__bf16*)out)[(size_t)((b*HH + h)*TT + t)*DD + d] = (__bf16)v;
                } else if (MODE == 1) {
                    const int b = row >> 11, t = row & (TT-1);
                    const int h = col >> 7,  d = col & (DD-1);
                    ((__bf16*)out)[(size_t)((b*HH + h)*DD + d)*TT + t] = (__bf16)v;
                } else {
                    ((float*)out)[(size_t)row*CC + col] = v;
                }
            }
        }
    }
}

// ---------------------------------------------------------------- attention
// Grid (B*H=32, NQB=16) = 512 blocks, 4 waves, 32 q-rows/wave (i=0,1).
// LDS 64KB: Ks[2] 32K dbuf + Vs 16K single (JIT: staged at tile start,
// vmcnt(4) before PV) + Ps 16K -> 2 blocks/CU. Shared kf/vf feed both
// q-groups (halves LDS reads per unit work — the measured bound).
// bh = blockIdx.x (bh%8 = XCD). qt = qy<8?15-qy:qy-8 (pair-balanced).
__global__ __launch_bounds__(256, 2) void attn_fwd(
    const __bf16* __restrict__ Q, const __bf16* __restrict__ K,
    const __bf16* __restrict__ Vt, __bf16* __restrict__ O)
{
    __shared__ __align__(16) __bf16 Ks[2][64*128];   // 32 KB (dbuf)
    __shared__ __align__(16) __bf16 Vs[128*64];      // 16 KB (single, JIT)
    __shared__ __align__(16) __bf16 Ps[4][32*64];    // 16 KB  (total 64 KB)

    const int bh = blockIdx.x;                    // b*H + h ; bh%8 == XCD
    const int qy = blockIdx.y;
    const int qt = (qy < 8) ? (15 - qy) : (qy - 8);   // pair-balanced, heavy 1st
    const int q0 = qt * 128;

    const int tid = threadIdx.x;
    const int w   = tid >> 6, lane = tid & 63;
    const int lo  = lane & 15, hi = lane >> 4;
    const int xr  = (lo & 7) << 4;         // read-side swizzle XOR (row bits)

    const int krow_l  = lane >> 4;                        // 0..3
    const int kcol_sw = ((lane & 15) << 4);               // 0..240 (bytes)
    const int vrow_l  = lane >> 3;                        // 0..7
    const int vcol_sw = (((lane & 7) ^ (lane >> 3)) << 3); // pre-swz elem off

    const size_t kbase = (size_t)bh * TT * DD;
    const size_t vbase = (size_t)bh * DD * TT;
    const int b = bh >> 4, h = bh & 15;
    const float SC = 0.12754613142f;   // D^-0.5 * log2(e)

    // all-ones B fragment: MFMA row-sum (denominator), layout-free
    bf16x8 vones;
    #pragma unroll
    for (int i = 0; i < 8; ++i) vones[i] = (__bf16)1.0f;

    auto stageK = [&](int buf, int kv0) {
        #pragma unroll
        for (int i = 0; i < 4; ++i) {
            const int c = 4*w + i;
            const int row = 4*c + krow_l;
            const int sw  = (kcol_sw ^ ((row & 7) << 4)) >> 1;
            g2lds16(K + kbase + (size_t)(kv0 + row)*DD + sw,
                    &Ks[buf][0] + c*512);
        }
    };
    auto stageV = [&](int kv0) {
        #pragma unroll
        for (int i = 0; i < 4; ++i) {
            const int c = 4*w + i;
            const int row = 8*c + vrow_l;
            g2lds16(Vt + vbase + (size_t)row*TT + kv0 + vcol_sw,
                    Vs + c*512);
        }
    };

    // Q fragments: rows q0 + w*32 + i*16 + lo
    const __bf16* Qbase = Q + (kbase + (size_t)(q0 + w*32 + lo) * DD);
    bf16x8 qf[2][4];
    #pragma unroll
    for (int i = 0; i < 2; ++i)
        #pragma unroll
        for (int kc = 0; kc < 4; ++kc)
            qf[i][kc] = *(const bf16x8*)(Qbase + (size_t)i*16*DD + kc*32 + hi*8);

    float mrow[2][4];
    #pragma unroll
    for (int i = 0; i < 2; ++i)
        #pragma unroll
        for (int r = 0; r < 4; ++r) mrow[i][r] = -1e30f;
    f32x4 oacc[2][8] = {};   // [i][dc]: rows q=i*16+4hi+r, cols d=dc*16+lo
    f32x4 sacc[2] = {};      // denominators, same row mapping

    const int qgb = q0 + w*32 + hi*4;      // + i*16 + r
    const int ntiles = 2*(qt + 1);         // KVB=64 tiles over kv 0..q0+127

    stageV(0);
    stageK(0, 0);
    asm volatile("s_waitcnt vmcnt(0)" ::: "memory");
    __builtin_amdgcn_s_barrier();
    int cur = 0;

    for (int t = 0; t < ntiles; ++t) {
        const int kv0 = t*64;
        if (t > 0) stageV(kv0);                       // V(t) JIT
        const bool havnext = (t + 1 < ntiles);
        if (havnext) stageK(cur ^ 1, kv0 + 64);       // K(t+1) prefetch

        const char* Kb = (const char*)&Ks[cur][0];
        const char* Vb = (const char*)Vs;

        // S = Q K^T : kf read once, feeds both q-groups
        f32x4 s[2][4];
        __builtin_amdgcn_s_setprio(1);
        #pragma unroll
        for (int st = 0; st < 4; ++st) {
            f32x4 a0 = {}, a1 = {};
            #pragma unroll
            for (int kc = 0; kc < 4; ++kc) {
                const bf16x8 kf = *(const bf16x8*)(
                    Kb + (st*16 + lo)*256 + ((kc*64 + hi*16) ^ xr));
                a0 = MFMA16(qf[0][kc], kf, a0);
                a1 = MFMA16(qf[1][kc], kf, a1);
            }
            s[0][st] = a0; s[1][st] = a1;
        }
        __builtin_amdgcn_s_setprio(0);

        // scale into log2 domain + causal mask (last 2 tiles) + row max
        float pmax[2][4];
        const bool diag = (t >= ntiles - 2);
        #pragma unroll
        for (int i = 0; i < 2; ++i) {
            #pragma unroll
            for (int r = 0; r < 4; ++r) {
                const int qg = qgb + i*16 + r;
                float mx = -1e30f;
                #pragma unroll
                for (int st = 0; st < 4; ++st) {
                    float v = s[i][st][r] * SC;
                    if (diag) {
                        const int kvg = kv0 + st*16 + lo;
                        v = (kvg > qg) ? -1e30f : v;
                    }
                    s[i][st][r] = v;
                    mx = fmaxf(mx, v);
                }
                #pragma unroll
                for (int msk = 1; msk < 16; msk <<= 1)
                    mx = fmaxf(mx, __shfl_xor(mx, msk, 64));
                pmax[i][r] = mx;
            }
        }

        // defer-max: rescale only when some row's max grew > THR (log2)
        bool need = false;
        #pragma unroll
        for (int i = 0; i < 2; ++i)
            #pragma unroll
            for (int r = 0; r < 4; ++r)
                need = need || (pmax[i][r] > mrow[i][r] + 11.5f);
        if (__any(need)) {
            float rsc[2][4];
            #pragma unroll
            for (int i = 0; i < 2; ++i)
                #pragma unroll
                for (int r = 0; r < 4; ++r) {
                    const float mnew = fmaxf(mrow[i][r], pmax[i][r]);
                    rsc[i][r] = __builtin_amdgcn_exp2f(mrow[i][r] - mnew);
                    mrow[i][r] = mnew;
                    sacc[i][r] *= rsc[i][r];
                }
            #pragma unroll
            for (int i = 0; i < 2; ++i)
                #pragma unroll
                for (int dc = 0; dc < 8; ++dc)
                    #pragma unroll
                    for (int r = 0; r < 4; ++r)
                        oacc[i][dc][r] *= rsc[i][r];
        }

        // P = exp2(s - m)
        #pragma unroll
        for (int i = 0; i < 2; ++i)
            #pragma unroll
            for (int r = 0; r < 4; ++r)
                #pragma unroll
                for (int st = 0; st < 4; ++st)
                    s[i][st][r] = __builtin_amdgcn_exp2f(s[i][st][r] - mrow[i][r]);

        // P -> per-wave swizzled LDS (wave-private: no barrier). 32 rows.
        char* Pw = (char*)&Ps[w][0];
        #pragma unroll
        for (int i = 0; i < 2; ++i)
            #pragma unroll
            for (int st = 0; st < 4; ++st)
                #pragma unroll
                for (int r = 0; r < 4; ++r) {
                    const int row = i*16 + hi*4 + r;
                    *(__bf16*)(Pw + row*128 + (((st*16 + lo)*2) ^ ((row & 7) << 4)))
                        = (__bf16)s[i][st][r];
                }

        // V(t) landed? (K(t+1)'s 4 loads may remain in flight)
        if (havnext) { asm volatile("s_waitcnt vmcnt(4)" ::: "memory"); }
        else         { asm volatile("s_waitcnt vmcnt(0)" ::: "memory"); }

        // PV: vf read once, feeds both q-groups; ones-column = denominator
        __builtin_amdgcn_s_setprio(1);
        #pragma unroll
        for (int kc2 = 0; kc2 < 2; ++kc2) {
            const bf16x8 pf0 = *(const bf16x8*)(
                Pw + lo*128 + ((kc2*64 + hi*16) ^ xr));
            const bf16x8 pf1 = *(const bf16x8*)(
                Pw + (16 + lo)*128 + ((kc2*64 + hi*16) ^ xr));
            #pragma unroll
            for (int dc = 0; dc < 8; ++dc) {
                const bf16x8 vf = *(const bf16x8*)(
                    Vb + (dc*16 + lo)*128 + ((kc2*64 + hi*16) ^ xr));
                oacc[0][dc] = MFMA16(pf0, vf, oacc[0][dc]);
                oacc[1][dc] = MFMA16(pf1, vf, oacc[1][dc]);
            }
            sacc[0] = MFMA16(pf0, vones, sacc[0]);
            sacc[1] = MFMA16(pf1, vones, sacc[1]);
        }
        __builtin_amdgcn_s_setprio(0);

        __syncthreads();   // drains vmcnt (K(t+1) landed) + V/K buffer safety
        cur ^= 1;
    }

    // epilogue: normalize by MFMA row sums, write [B,T,H*D] bf16
    #pragma unroll
    for (int i = 0; i < 2; ++i) {
        #pragma unroll
        for (int r = 0; r < 4; ++r) {
            const float inv = 1.f / sacc[i][r];
            const int qg = qgb + i*16 + r;
            #pragma unroll
            for (int dc = 0; dc < 8; ++dc) {
                const int d = dc*16 + lo;
                O[(size_t)(b*TT + qg)*CC + h*DD + d] = (__bf16)(oacc[i][dc][r] * inv);
            }
        }
    }
}

// ---------------------------------------------------------------- launch
extern "C" void kernel_launch(void* const* d_in, const int* in_sizes, int n_in,
                              void* d_out, int out_size, void* d_ws, size_t ws_size,
                              hipStream_t stream) {
    const float* x  = (const float*)d_in[0];
    // d_in[1] = mask (causal, implemented analytically)
    const float* wq = (const float*)d_in[2];
    const float* wk = (const float*)d_in[3];
    const float* wv = (const float*)d_in[4];
    const float* wo = (const float*)d_in[5];

    char* p = (char*)d_ws;
    __bf16* xb  = (__bf16*)p; p += (size_t)MM*CC*2;   // also reused as attn-out
    __bf16* wqb = (__bf16*)p; p += (size_t)CC*CC*2;   // wq,wk,wv,wo contiguous
    __bf16* wkb = (__bf16*)p; p += (size_t)CC*CC*2;
    __bf16* wvb = (__bf16*)p; p += (size_t)CC*CC*2;
    __bf16* wob = (__bf16*)p; p += (size_t)CC*CC*2;
    __bf16* Qb  = (__bf16*)p; p += (size_t)MM*CC*2;
    __bf16* Kb  = (__bf16*)p; p += (size_t)MM*CC*2;
    __bf16* Vtb = (__bf16*)p; p += (size_t)MM*CC*2;
    __bf16* AOb = xb;  // x no longer needed after QKV GEMMs (stream-ordered)

    cvt_all<<<24576, 256, 0, stream>>>(x, wq, wk, wv, wo, xb);

    const dim3 gg(CC/128, MM/256);   // (16, 16) = 256 blocks = 1/CU
    gemm_bt<0><<<gg, 512, 0, stream>>>(xb, wqb, Qb);
    gemm_bt<0><<<gg, 512, 0, stream>>>(xb, wkb, Kb);
    gemm_bt<1><<<gg, 512, 0, stream>>>(xb, wvb, Vtb);

    attn_fwd<<<dim3(BB*HH, NQB), 256, 0, stream>>>(Qb, Kb, Vtb, AOb);

    gemm_bt<2><<<gg, 512, 0, stream>>>(AOb, wob, (void*)d_out);
}

// Round 18
// 222.202 us; speedup vs baseline: 1.1262x; 1.1262x over previous
//
#include <hip/hip_runtime.h>
#include <hip/hip_bf16.h>

// Causal attention block: out = softmax(mask(QK^T/sqrt(D))) V projections.
// B=2, T=2048, C=2048, H=16, D=128. fp32 I/O, bf16 MFMA compute internally.
//
// Pipeline:
//   1. cvt_all: x + 4 weights f32->bf16 in ONE launch
//   2. gemm_qk: fused Q+K = x@[wq;wk].T (N=4096, 256x256 tile, 128x64 wave
//        tile -> LDS-read:MFMA ratio 0.375 vs 0.5) -> [B,H,T,D] x2
//      gemm_bt<1>: V = x@wv.T -> [B,H,D,T]
//   3. attn_fwd: R16-frozen (KVB=64 dbuf, causal pairing, bh->XCD map,
//        exp2 softmax, defer-max, ones-MFMA denominator, 72KB LDS).
//   4. gemm_bt<2>: out = attn@wo.T -> fp32 d_out
//
// gemm_bt (V/WO): 256x128 tile, BK=64, TRIPLE-buffered 144KB LDS, ONE
// barrier + vmcnt(6)/K-tile (R16-verified). gemm_qk: 256x256, BK=64,
// DOUBLE-buffered 128KB (tile compute ~2064cy > 900cy HBM latency),
// 2-phase, vmcnt(0)+barrier per tile. Both XCD-swizzled + setprio.

#define BB 2
#define TT 2048
#define CC 2048
#define HH 16
#define DD 128
#define MM (BB*TT)   // 4096
#define NQT (TT/64)  // 32 q-tiles (64 rows each)
#define GNT (CC/64)  // 32 K-tiles in GEMM

typedef __bf16 bf16x8 __attribute__((ext_vector_type(8)));
typedef __bf16 bf16x4 __attribute__((ext_vector_type(4)));
typedef float  f32x4  __attribute__((ext_vector_type(4)));

#define MFMA16(a, b, c) __builtin_amdgcn_mfma_f32_16x16x32_bf16((a), (b), (c), 0, 0, 0)

__device__ __forceinline__ void g2lds16(const void* g, void* l) {
    __builtin_amdgcn_global_load_lds(
        (const __attribute__((address_space(1))) void*)g,
        (__attribute__((address_space(3))) void*)l,
        16, 0, 0);
}

// ---------------------------------------------------------------- convert
__global__ __launch_bounds__(256) void cvt_all(
    const float* __restrict__ x,  const float* __restrict__ wq,
    const float* __restrict__ wk, const float* __restrict__ wv,
    const float* __restrict__ wo, __bf16* __restrict__ out_base)
{
    const int idx = blockIdx.x * 256 + threadIdx.x;   // < 6291456
    const float* in; int off;
    if (idx < (1 << 21)) { in = x; off = idx; }
    else {
        const int r = idx - (1 << 21);
        const int k = r >> 20;
        in  = (k == 0) ? wq : (k == 1) ? wk : (k == 2) ? wv : wo;
        off = r & ((1 << 20) - 1);
    }
    const float4 v = ((const float4*)in)[off];
    bf16x4 o;
    o.x = (__bf16)v.x; o.y = (__bf16)v.y;
    o.z = (__bf16)v.z; o.w = (__bf16)v.w;
    ((bf16x4*)out_base)[idx] = o;
}

// ---------------------------------------------------------------- gemm_qk
// Fused Q+K: C[m][n] = sum_k A[m][k]*Wt[n][k], M=4096, N=4096 (wq;wk).
// BM=BN=256, BK=64; grid (16,16)=256 blocks=1/CU. 8 waves 2Mx4N ->
// wave tile 128x64 (8x4 frags). LDS double-buffer 128KB. Per tile:
// ph0 {rdA/rdB ks0, stage A(t+1), 32 MFMA}; ph1 {rd ks1, stage B(t+1),
// 32 MFMA, vmcnt(0), barrier}. seg = col>>11 selects Q/K output.
__global__ __launch_bounds__(512, 2) void gemm_qk(
    const __bf16* __restrict__ A, const __bf16* __restrict__ Wt,
    __bf16* __restrict__ out)
{
    __shared__ __align__(16) __bf16 As[2][256*64];      // 64 KB, 128B rows
    __shared__ __align__(16) __bf16 Bs[2][2][256*32];   // 64 KB, 64B rows, k-sliced

    const int tid = threadIdx.x;
    const int w   = tid >> 6, lane = tid & 63;
    const int wm  = w >> 2,  wn  = w & 3;         // 2M x 4N
    const int lo  = lane & 15, hi = lane >> 4;
    const int xr  = (lo & 7) << 4;          // A read swizzle (8 slots/128B row)
    const int xb2 = ((lo >> 1) & 3) << 4;   // B read swizzle (4 slots/64B row)

    // XCD swizzle: each XCD owns 2 n-supertiles (B panel 2MB, L2-resident)
    const int bid = blockIdx.y * gridDim.x + blockIdx.x;
    const int xcd = bid & 7, loc = bid >> 3;
    const int n0  = (2*xcd + (loc & 1)) * 256;
    const int m0  = (loc >> 1) * 256;

    const int ar   = tid >> 3, as_ = tid & 7;            // A: 64 rows x 8 slots
    const int acol = ((as_ ^ (ar & 7)) << 3);
    const int brr  = tid >> 2, bs_ = tid & 3;            // B: 128 rows x 4 slots
    const int bcol = ((bs_ ^ ((brr >> 1) & 3)) << 3);

    auto stageA = [&](int buf, int kt) {                 // 4 loads (32KB)
        #pragma unroll
        for (int j = 0; j < 4; ++j)
            g2lds16(A + (size_t)(m0 + j*64 + ar)*CC + kt*64 + acol,
                    (char*)&As[buf][0] + j*8192 + w*1024);
    };
    auto stageB = [&](int buf, int kt) {                 // 4 loads (32KB)
        #pragma unroll
        for (int ks = 0; ks < 2; ++ks)
            #pragma unroll
            for (int jb = 0; jb < 2; ++jb)
                g2lds16(Wt + (size_t)(n0 + jb*128 + brr)*CC + kt*64 + ks*32 + bcol,
                        (char*)&Bs[buf][ks][0] + jb*8192 + w*1024);
    };
    auto rdA = [&](bf16x8* af, int buf, int ks) {
        const char* base = (const char*)&As[buf][0];
        #pragma unroll
        for (int mf = 0; mf < 8; ++mf) {
            const int r = wm*128 + mf*16 + lo;
            af[mf] = *(const bf16x8*)(base + r*128 + ((ks*64 + hi*16) ^ xr));
        }
    };
    auto rdB = [&](bf16x8* bv, int buf, int ks) {
        const char* base = (const char*)&Bs[buf][ks][0];
        #pragma unroll
        for (int nf = 0; nf < 4; ++nf) {
            const int n = wn*64 + nf*16 + lo;
            bv[nf] = *(const bf16x8*)(base + n*64 + ((hi*16) ^ xb2));
        }
    };

    f32x4 acc[8][4] = {};

    stageA(0, 0); stageB(0, 0);
    asm volatile("s_waitcnt vmcnt(0)" ::: "memory");
    __builtin_amdgcn_s_barrier();

    int buf = 0;
    #pragma unroll 1
    for (int t = 0; t < GNT; ++t) {
        const bool hn = (t + 1 < GNT);
        // phase 0 (ks=0)
        {
            bf16x8 af[8], bv[4];
            rdA(af, buf, 0); rdB(bv, buf, 0);
            if (hn) stageA(buf ^ 1, t + 1);
            __builtin_amdgcn_s_setprio(1);
            #pragma unroll
            for (int mf = 0; mf < 8; ++mf)
                #pragma unroll
                for (int nf = 0; nf < 4; ++nf)
                    acc[mf][nf] = MFMA16(af[mf], bv[nf], acc[mf][nf]);
            __builtin_amdgcn_s_setprio(0);
        }
        // phase 1 (ks=1) + tile-end sync
        {
            bf16x8 af[8], bv[4];
            rdA(af, buf, 1); rdB(bv, buf, 1);
            if (hn) stageB(buf ^ 1, t + 1);
            __builtin_amdgcn_s_setprio(1);
            #pragma unroll
            for (int mf = 0; mf < 8; ++mf)
                #pragma unroll
                for (int nf = 0; nf < 4; ++nf)
                    acc[mf][nf] = MFMA16(af[mf], bv[nf], acc[mf][nf]);
            __builtin_amdgcn_s_setprio(0);
            if (hn) {
                asm volatile("s_waitcnt vmcnt(0)" ::: "memory"); // t+1 landed
                __builtin_amdgcn_s_barrier();                    // buf reuse safe
            }
        }
        buf ^= 1;
    }

    // epilogue: seg 0 = Q, seg 1 = K; both [B,H,T,D] bf16
    #pragma unroll
    for (int mf = 0; mf < 8; ++mf) {
        #pragma unroll
        for (int nf = 0; nf < 4; ++nf) {
            #pragma unroll
            for (int r = 0; r < 4; ++r) {
                const int row = m0 + wm*128 + mf*16 + hi*4 + r;   // m
                const int col = n0 + wn*64 + nf*16 + lo;          // n (0..4095)
                const int seg = col >> 11;
                const int c2  = col & (CC-1);
                const int b = row >> 11, t_ = row & (TT-1);
                const int h = c2 >> 7,  d  = c2 & (DD-1);
                __bf16* dst = out + (size_t)seg * MM * CC;
                dst[(size_t)((b*HH + h)*TT + t_)*DD + d] = (__bf16)acc[mf][nf][r];
            }
        }
    }
}

// ---------------------------------------------------------------- GEMM (B^T)
// (R16-verified: ~31us each; ONE barrier + vmcnt(6) per K-tile)
// MODE 1: bf16 [B,H,D,T] (V transposed); MODE 2: fp32 row-major (WO).
template<int MODE>
__global__ __launch_bounds__(512, 2) void gemm_bt(
    const __bf16* __restrict__ A, const __bf16* __restrict__ Wt,
    void* __restrict__ out)
{
    __shared__ __align__(16) __bf16 As[3][256*64];      // 96 KB, 128B rows
    __shared__ __align__(16) __bf16 Bs[3][2][128*32];   // 48 KB, 64B rows, k-sliced

    const int tid = threadIdx.x;
    const int w   = tid >> 6, lane = tid & 63;
    const int wm  = w >> 1,  wn  = w & 1;
    const int lo  = lane & 15, hi = lane >> 4;
    const int xr  = (lo & 7) << 4;
    const int xb2 = ((lo >> 1) & 3) << 4;

    const int bid   = blockIdx.y * gridDim.x + blockIdx.x;
    const int xcd   = bid & 7, loc = bid >> 3;
    const int n0    = (2*xcd + (loc & 1)) * 128;
    const int m0    = (loc >> 1) * 256;

    const int ar   = tid >> 3, as_ = tid & 7;
    const int acol = ((as_ ^ (ar & 7)) << 3);
    const int br   = tid >> 2, bs_ = tid & 3;
    const int bcol = ((bs_ ^ ((br >> 1) & 3)) << 3);

    auto stageA3a = [&](int buf, int kt) {               // A loads j=0,1,2
        #pragma unroll
        for (int j = 0; j < 3; ++j)
            g2lds16(A + (size_t)(m0 + j*64 + ar)*CC + kt*64 + acol,
                    (char*)&As[buf][0] + j*8192 + w*1024);
    };
    auto stageA3b = [&](int buf, int kt) {               // A j=3 + B kh=0,1
        g2lds16(A + (size_t)(m0 + 3*64 + ar)*CC + kt*64 + acol,
                (char*)&As[buf][0] + 3*8192 + w*1024);
        #pragma unroll
        for (int kh = 0; kh < 2; ++kh)
            g2lds16(Wt + (size_t)(n0 + br)*CC + kt*64 + kh*32 + bcol,
                    (char*)&Bs[buf][kh][0] + w*1024);
    };
    auto rdA = [&](bf16x8* af, int buf, int ks) {
        const char* base = (const char*)&As[buf][0];
        #pragma unroll
        for (int mf = 0; mf < 4; ++mf) {
            const int r = wm*64 + mf*16 + lo;
            af[mf] = *(const bf16x8*)(base + r*128 + ((ks*64 + hi*16) ^ xr));
        }
    };
    auto rdB = [&](bf16x8* bv, int buf, int ks) {
        const char* base = (const char*)&Bs[buf][ks][0];
        #pragma unroll
        for (int nf = 0; nf < 4; ++nf) {
            const int n = wn*64 + nf*16 + lo;
            bv[nf] = *(const bf16x8*)(base + n*64 + ((hi*16) ^ xb2));
        }
    };

    f32x4 acc[4][4] = {};

    stageA3a(0, 0); stageA3b(0, 0);
    stageA3a(1, 1); stageA3b(1, 1);
    asm volatile("s_waitcnt vmcnt(6)" ::: "memory");
    __builtin_amdgcn_s_barrier();

    int rb = 0;   // read buffer = t%3
    #pragma unroll 1
    for (int t = 0; t < GNT - 2; ++t) {
        const int sb = (rb == 0) ? 2 : rb - 1;   // (t+2)%3
        {
            bf16x8 af[4], bv[4];
            rdA(af, rb, 0); rdB(bv, rb, 0);
            stageA3a(sb, t + 2);
            __builtin_amdgcn_s_setprio(1);
            #pragma unroll
            for (int mf = 0; mf < 4; ++mf)
                #pragma unroll
                for (int nf = 0; nf < 4; ++nf)
                    acc[mf][nf] = MFMA16(af[mf], bv[nf], acc[mf][nf]);
            __builtin_amdgcn_s_setprio(0);
        }
        {
            bf16x8 af[4], bv[4];
            rdA(af, rb, 1); rdB(bv, rb, 1);
            stageA3b(sb, t + 2);
            __builtin_amdgcn_s_setprio(1);
            #pragma unroll
            for (int mf = 0; mf < 4; ++mf)
                #pragma unroll
                for (int nf = 0; nf < 4; ++nf)
                    acc[mf][nf] = MFMA16(af[mf], bv[nf], acc[mf][nf]);
            __builtin_amdgcn_s_setprio(0);
            asm volatile("s_waitcnt vmcnt(6)" ::: "memory"); // t+1 landed
            __builtin_amdgcn_s_barrier();                    // tile boundary
        }
        rb = (rb == 2) ? 0 : rb + 1;
    }
    {   // peeled t = GNT-2 (no staging)
        bf16x8 af[4], bv[4];
        rdA(af, rb, 0); rdB(bv, rb, 0);
        #pragma unroll
        for (int mf = 0; mf < 4; ++mf)
            #pragma unroll
            for (int nf = 0; nf < 4; ++nf)
                acc[mf][nf] = MFMA16(af[mf], bv[nf], acc[mf][nf]);
        rdA(af, rb, 1); rdB(bv, rb, 1);
        #pragma unroll
        for (int mf = 0; mf < 4; ++mf)
            #pragma unroll
            for (int nf = 0; nf < 4; ++nf)
                acc[mf][nf] = MFMA16(af[mf], bv[nf], acc[mf][nf]);
        asm volatile("s_waitcnt vmcnt(0)" ::: "memory");     // last tile landed
        __builtin_amdgcn_s_barrier();
        rb = (rb == 2) ? 0 : rb + 1;
    }
    {   // peeled t = GNT-1 (compute only)
        bf16x8 af[4], bv[4];
        rdA(af, rb, 0); rdB(bv, rb, 0);
        #pragma unroll
        for (int mf = 0; mf < 4; ++mf)
            #pragma unroll
            for (int nf = 0; nf < 4; ++nf)
                acc[mf][nf] = MFMA16(af[mf], bv[nf], acc[mf][nf]);
        rdA(af, rb, 1); rdB(bv, rb, 1);
        #pragma unroll
        for (int mf = 0; mf < 4; ++mf)
            #pragma unroll
            for (int nf = 0; nf < 4; ++nf)
                acc[mf][nf] = MFMA16(af[mf], bv[nf], acc[mf][nf]);
    }

    #pragma unroll
    for (int mf = 0; mf < 4; ++mf) {
        #pragma unroll
        for (int nf = 0; nf < 4; ++nf) {
            #pragma unroll
            for (int r = 0; r < 4; ++r) {
                const int row = m0 + wm*64 + mf*16 + hi*4 + r;   // m
                const int col = n0 + wn*64 + nf*16 + lo;         // n
                const float v = acc[mf][nf][r];
                if (MODE == 1) {
                    const int b = row >> 11, t = row & (TT-1);
                    const int h = col >> 7,  d = col & (DD-1);
                    ((__bf16*)out)[(size_t)((b*HH + h)*DD + d)*TT + t] = (__bf16)v;
                } else {
                    ((float*)out)[(size_t)row*CC + col] = v;
                }
            }
        }
    }
}

// ---------------------------------------------------------------- attention
// R16-frozen: grid (NQT/2, B*H) = 512 blocks, 4 waves, causal pairing
// (heavy+light = uniform 33 KV-tiles/block), bh = lid&31 XCD map, KVB=64
// double-buffered swizzled LDS (72KB -> 2 blocks/CU), exp2 softmax,
// defer-max, ones-MFMA denominator (no sum shfl reduce).
__global__ __launch_bounds__(256, 2) void attn_fwd(
    const __bf16* __restrict__ Q, const __bf16* __restrict__ K,
    const __bf16* __restrict__ Vt, __bf16* __restrict__ O)
{
    __shared__ __align__(16) __bf16 Ks[2][64*128];   // 32 KB
    __shared__ __align__(16) __bf16 Vs[2][128*64];   // 32 KB
    __shared__ __align__(16) __bf16 Ps[4][16*64];    //  8 KB

    const int lid   = blockIdx.y * gridDim.x + blockIdx.x;
    const int bh    = lid & 31;            // b*H + h  (bh%8 == XCD id)
    const int pairx = lid >> 5;            // 0..15 causal pair index
    const int tid = threadIdx.x;
    const int w   = tid >> 6, lane = tid & 63;
    const int lo  = lane & 15, hi = lane >> 4;
    const int xr  = (lo & 7) << 4;         // read-side swizzle XOR (row bits)

    const int krow_l  = lane >> 4;                        // 0..3
    const int kcol_sw = ((lane & 15) << 4);               // 0..240 (bytes)
    const int vrow_l  = lane >> 3;                        // 0..7
    const int vcol_sw = (((lane & 7) ^ (lane >> 3)) << 3); // pre-swz elem off

    const size_t kbase = (size_t)bh * TT * DD;
    const size_t vbase = (size_t)bh * DD * TT;
    const int b = bh >> 4, h = bh & 15;
    const float SC = 0.12754613142f;   // D^-0.5 * log2(e)

    bf16x8 vones;
    #pragma unroll
    for (int i = 0; i < 8; ++i) vones[i] = (__bf16)1.0f;

    auto stage = [&](int buf, int kv0) {
        #pragma unroll
        for (int i = 0; i < 4; ++i) {
            const int c = 4*w + i;
            {   // K: row = 4c + krow_l; src col byte = kcol_sw ^ ((row&7)<<4)
                const int row = 4*c + krow_l;
                const int sw  = (kcol_sw ^ ((row & 7) << 4)) >> 1;
                g2lds16(K + kbase + (size_t)(kv0 + row)*DD + sw,
                        &Ks[buf][0] + c*512);
            }
            {   // Vt: row(d) = 8c + vrow_l
                const int row = 8*c + vrow_l;
                g2lds16(Vt + vbase + (size_t)row*TT + kv0 + vcol_sw,
                        &Vs[buf][0] + c*512);
            }
        }
    };

    #pragma unroll 1
    for (int half = 0; half < 2; ++half) {
        const int qt = half ? pairx : (NQT - 1 - pairx);
        const int q0 = qt * 64;

        const __bf16* Qbase = Q + (kbase + (size_t)(q0 + w*16 + lo) * DD);
        bf16x8 qf[4];
        #pragma unroll
        for (int kc = 0; kc < 4; ++kc)
            qf[kc] = *(const bf16x8*)(Qbase + kc*32 + hi*8);

        float mrow[4];
        #pragma unroll
        for (int r = 0; r < 4; ++r) mrow[r] = -1e30f;
        f32x4 oacc[8] = {};   // out rows q=4*hi+r, cols d = dc*16+lo
        f32x4 sacc = {};      // row-sum accumulator (denominator)

        const int qg_base = q0 + w*16 + hi*4;  // + r
        const int ntiles  = qt + 1;            // causal: kv tiles 0..qt

        stage(0, 0);
        __syncthreads();
        int cur = 0;

        for (int t = 0; t < ntiles; ++t) {
            const int kv0 = t*64;
            if (t + 1 < ntiles) stage(cur ^ 1, (t+1)*64);

            const char* Kb = (const char*)&Ks[cur][0];
            const char* Vb = (const char*)&Vs[cur][0];

            // S = Q K^T : lane holds S[q=4hi+r][kv=st*16+lo]
            f32x4 s[4];
            __builtin_amdgcn_s_setprio(1);
            #pragma unroll
            for (int st = 0; st < 4; ++st) {
                f32x4 a = {};
                #pragma unroll
                for (int kc = 0; kc < 4; ++kc) {
                    const bf16x8 kf = *(const bf16x8*)(
                        Kb + (st*16 + lo)*256 + ((kc*64 + hi*16) ^ xr));
                    a = MFMA16(qf[kc], kf, a);
                }
                s[st] = a;
            }
            __builtin_amdgcn_s_setprio(0);

            // scale into log2 domain + (diagonal-only) causal mask + row max
            float pmax[4];
            const bool diag = (t == ntiles - 1);
            #pragma unroll
            for (int r = 0; r < 4; ++r) {
                const int qg = qg_base + r;
                float mx = -1e30f;
                #pragma unroll
                for (int st = 0; st < 4; ++st) {
                    float v = s[st][r] * SC;
                    if (diag) {
                        const int kvg = kv0 + st*16 + lo;
                        v = (kvg > qg) ? -1e30f : v;
                    }
                    s[st][r] = v;
                    mx = fmaxf(mx, v);
                }
                #pragma unroll
                for (int msk = 1; msk < 16; msk <<= 1)
                    mx = fmaxf(mx, __shfl_xor(mx, msk, 64));
                pmax[r] = mx;
            }

            // defer-max: only rescale when some row's max grew > THR (log2)
            bool need = false;
            #pragma unroll
            for (int r = 0; r < 4; ++r)
                need = need || (pmax[r] > mrow[r] + 11.5f);
            if (__any(need)) {
                float rsc[4];
                #pragma unroll
                for (int r = 0; r < 4; ++r) {
                    const float mnew = fmaxf(mrow[r], pmax[r]);
                    rsc[r]  = __builtin_amdgcn_exp2f(mrow[r] - mnew);
                    mrow[r] = mnew;
                    sacc[r] *= rsc[r];
                }
                #pragma unroll
                for (int dc = 0; dc < 8; ++dc)
                    #pragma unroll
                    for (int r = 0; r < 4; ++r)
                        oacc[dc][r] *= rsc[r];
            }

            // P = exp2(s - m); denominator via PV ones-column below
            #pragma unroll
            for (int r = 0; r < 4; ++r)
                #pragma unroll
                for (int st = 0; st < 4; ++st)
                    s[st][r] = __builtin_amdgcn_exp2f(s[st][r] - mrow[r]);

            // P -> per-wave swizzled LDS (wave-private: no barrier)
            char* Pw = (char*)&Ps[w][0];
            #pragma unroll
            for (int st = 0; st < 4; ++st)
                #pragma unroll
                for (int r = 0; r < 4; ++r) {
                    const int row = hi*4 + r;
                    *(__bf16*)(Pw + row*128 + (((st*16 + lo)*2) ^ ((row & 7) << 4)))
                        = (__bf16)s[st][r];
                }

            // PV: out[q][d] += P[q][kv] V[kv][d];  sacc += P row-sums
            __builtin_amdgcn_s_setprio(1);
            #pragma unroll
            for (int kc2 = 0; kc2 < 2; ++kc2) {
                const bf16x8 pf = *(const bf16x8*)(
                    Pw + lo*128 + ((kc2*64 + hi*16) ^ xr));
                #pragma unroll
                for (int dc = 0; dc < 8; ++dc) {
                    const bf16x8 vf = *(const bf16x8*)(
                        Vb + (dc*16 + lo)*128 + ((kc2*64 + hi*16) ^ xr));
                    oacc[dc] = MFMA16(pf, vf, oacc[dc]);
                }
                sacc = MFMA16(pf, vones, sacc);   // denominator (free pipe)
            }
            __builtin_amdgcn_s_setprio(0);

            __syncthreads();   // drains prefetch vmcnt + protects buffer swap
            cur ^= 1;
        }

        // epilogue: normalize by MFMA-accumulated row sums, write bf16
        #pragma unroll
        for (int r = 0; r < 4; ++r) {
            const float inv = 1.f / sacc[r];
            const int qg = qg_base + r;
            #pragma unroll
            for (int dc = 0; dc < 8; ++dc) {
                const int d = dc*16 + lo;
                O[(size_t)(b*TT + qg)*CC + h*DD + d] = (__bf16)(oacc[dc][r] * inv);
            }
        }
    }
}

// ---------------------------------------------------------------- launch
extern "C" void kernel_launch(void* const* d_in, const int* in_sizes, int n_in,
                              void* d_out, int out_size, void* d_ws, size_t ws_size,
                              hipStream_t stream) {
    const float* x  = (const float*)d_in[0];
    // d_in[1] = mask (causal, implemented analytically)
    const float* wq = (const float*)d_in[2];
    const float* wk = (const float*)d_in[3];
    const float* wv = (const float*)d_in[4];
    const float* wo = (const float*)d_in[5];

    char* p = (char*)d_ws;
    __bf16* xb  = (__bf16*)p; p += (size_t)MM*CC*2;   // also reused as attn-out
    __bf16* wqb = (__bf16*)p; p += (size_t)CC*CC*2;   // wq,wk contiguous (fused N=4096)
    __bf16* wkb = (__bf16*)p; p += (size_t)CC*CC*2;
    __bf16* wvb = (__bf16*)p; p += (size_t)CC*CC*2;
    __bf16* wob = (__bf16*)p; p += (size_t)CC*CC*2;
    __bf16* Qb  = (__bf16*)p; p += (size_t)MM*CC*2;   // Q,K contiguous (gemm_qk out)
    __bf16* Kb  = (__bf16*)p; p += (size_t)MM*CC*2;
    __bf16* Vtb = (__bf16*)p; p += (size_t)MM*CC*2;
    __bf16* AOb = xb;  // x no longer needed after QKV GEMMs (stream-ordered)
    (void)wkb;

    cvt_all<<<24576, 256, 0, stream>>>(x, wq, wk, wv, wo, xb);

    // fused Q+K: N=4096, 256x256 tiles, grid (16,16) = 256 blocks = 1/CU
    gemm_qk<<<dim3(16, 16), 512, 0, stream>>>(xb, wqb, Qb);
    // V: proven 256x128 structure
    gemm_bt<1><<<dim3(16, 16), 512, 0, stream>>>(xb, wvb, Vtb);

    attn_fwd<<<dim3(NQT/2, BB*HH), 256, 0, stream>>>(Qb, Kb, Vtb, AOb);

    gemm_bt<2><<<dim3(16, 16), 512, 0, stream>>>(AOb, wob, (void*)d_out);
}

// Round 19
// 212.588 us; speedup vs baseline: 1.1772x; 1.0452x over previous
//
#include <hip/hip_runtime.h>
#include <hip/hip_bf16.h>

// Causal attention block: out = softmax(mask(QK^T/sqrt(D))) V projections.
// B=2, T=2048, C=2048, H=16, D=128. fp32 I/O, bf16 MFMA compute internally.
//
// Pipeline:
//   1. cvt_all: x + 4 weights f32->bf16 in ONE launch
//   2. gemm_qk: fused Q+K = x@[wq;wk].T (N=4096, 256x256 tile) -> [B,H,T,D]x2
//      gemm_bt<1>: V = x@wv.T -> [B,H,D,T]
//   3. attn_fwd: R16 structure + lazy max-reduce: cross-lane max shuffles
//        (16 ds_bpermute/tile, ~17% of LDS-pipe issue) only run when a
//        lane-local conservative check triggers the defer-max rescale.
//   4. gemm_bt<2>: out = attn@wo.T -> fp32 d_out

#define BB 2
#define TT 2048
#define CC 2048
#define HH 16
#define DD 128
#define MM (BB*TT)   // 4096
#define NQT (TT/64)  // 32 q-tiles (64 rows each)
#define GNT (CC/64)  // 32 K-tiles in GEMM

typedef __bf16 bf16x8 __attribute__((ext_vector_type(8)));
typedef __bf16 bf16x4 __attribute__((ext_vector_type(4)));
typedef float  f32x4  __attribute__((ext_vector_type(4)));

#define MFMA16(a, b, c) __builtin_amdgcn_mfma_f32_16x16x32_bf16((a), (b), (c), 0, 0, 0)

__device__ __forceinline__ void g2lds16(const void* g, void* l) {
    __builtin_amdgcn_global_load_lds(
        (const __attribute__((address_space(1))) void*)g,
        (__attribute__((address_space(3))) void*)l,
        16, 0, 0);
}

// ---------------------------------------------------------------- convert
__global__ __launch_bounds__(256) void cvt_all(
    const float* __restrict__ x,  const float* __restrict__ wq,
    const float* __restrict__ wk, const float* __restrict__ wv,
    const float* __restrict__ wo, __bf16* __restrict__ out_base)
{
    const int idx = blockIdx.x * 256 + threadIdx.x;   // < 6291456
    const float* in; int off;
    if (idx < (1 << 21)) { in = x; off = idx; }
    else {
        const int r = idx - (1 << 21);
        const int k = r >> 20;
        in  = (k == 0) ? wq : (k == 1) ? wk : (k == 2) ? wv : wo;
        off = r & ((1 << 20) - 1);
    }
    const float4 v = ((const float4*)in)[off];
    bf16x4 o;
    o.x = (__bf16)v.x; o.y = (__bf16)v.y;
    o.z = (__bf16)v.z; o.w = (__bf16)v.w;
    ((bf16x4*)out_base)[idx] = o;
}

// ---------------------------------------------------------------- gemm_qk
// Fused Q+K: N=4096 (wq;wk), BM=BN=256, BK=64; grid (16,16)=256=1/CU.
// 8 waves 2Mx4N -> wave tile 128x64. LDS double-buffer 128KB.
__global__ __launch_bounds__(512, 2) void gemm_qk(
    const __bf16* __restrict__ A, const __bf16* __restrict__ Wt,
    __bf16* __restrict__ out)
{
    __shared__ __align__(16) __bf16 As[2][256*64];      // 64 KB, 128B rows
    __shared__ __align__(16) __bf16 Bs[2][2][256*32];   // 64 KB, 64B rows, k-sliced

    const int tid = threadIdx.x;
    const int w   = tid >> 6, lane = tid & 63;
    const int wm  = w >> 2,  wn  = w & 3;         // 2M x 4N
    const int lo  = lane & 15, hi = lane >> 4;
    const int xr  = (lo & 7) << 4;
    const int xb2 = ((lo >> 1) & 3) << 4;

    const int bid = blockIdx.y * gridDim.x + blockIdx.x;
    const int xcd = bid & 7, loc = bid >> 3;
    const int n0  = (2*xcd + (loc & 1)) * 256;
    const int m0  = (loc >> 1) * 256;

    const int ar   = tid >> 3, as_ = tid & 7;
    const int acol = ((as_ ^ (ar & 7)) << 3);
    const int brr  = tid >> 2, bs_ = tid & 3;
    const int bcol = ((bs_ ^ ((brr >> 1) & 3)) << 3);

    auto stageA = [&](int buf, int kt) {
        #pragma unroll
        for (int j = 0; j < 4; ++j)
            g2lds16(A + (size_t)(m0 + j*64 + ar)*CC + kt*64 + acol,
                    (char*)&As[buf][0] + j*8192 + w*1024);
    };
    auto stageB = [&](int buf, int kt) {
        #pragma unroll
        for (int ks = 0; ks < 2; ++ks)
            #pragma unroll
            for (int jb = 0; jb < 2; ++jb)
                g2lds16(Wt + (size_t)(n0 + jb*128 + brr)*CC + kt*64 + ks*32 + bcol,
                        (char*)&Bs[buf][ks][0] + jb*8192 + w*1024);
    };
    auto rdA = [&](bf16x8* af, int buf, int ks) {
        const char* base = (const char*)&As[buf][0];
        #pragma unroll
        for (int mf = 0; mf < 8; ++mf) {
            const int r = wm*128 + mf*16 + lo;
            af[mf] = *(const bf16x8*)(base + r*128 + ((ks*64 + hi*16) ^ xr));
        }
    };
    auto rdB = [&](bf16x8* bv, int buf, int ks) {
        const char* base = (const char*)&Bs[buf][ks][0];
        #pragma unroll
        for (int nf = 0; nf < 4; ++nf) {
            const int n = wn*64 + nf*16 + lo;
            bv[nf] = *(const bf16x8*)(base + n*64 + ((hi*16) ^ xb2));
        }
    };

    f32x4 acc[8][4] = {};

    stageA(0, 0); stageB(0, 0);
    asm volatile("s_waitcnt vmcnt(0)" ::: "memory");
    __builtin_amdgcn_s_barrier();

    int buf = 0;
    #pragma unroll 1
    for (int t = 0; t < GNT; ++t) {
        const bool hn = (t + 1 < GNT);
        {
            bf16x8 af[8], bv[4];
            rdA(af, buf, 0); rdB(bv, buf, 0);
            if (hn) stageA(buf ^ 1, t + 1);
            __builtin_amdgcn_s_setprio(1);
            #pragma unroll
            for (int mf = 0; mf < 8; ++mf)
                #pragma unroll
                for (int nf = 0; nf < 4; ++nf)
                    acc[mf][nf] = MFMA16(af[mf], bv[nf], acc[mf][nf]);
            __builtin_amdgcn_s_setprio(0);
        }
        {
            bf16x8 af[8], bv[4];
            rdA(af, buf, 1); rdB(bv, buf, 1);
            if (hn) stageB(buf ^ 1, t + 1);
            __builtin_amdgcn_s_setprio(1);
            #pragma unroll
            for (int mf = 0; mf < 8; ++mf)
                #pragma unroll
                for (int nf = 0; nf < 4; ++nf)
                    acc[mf][nf] = MFMA16(af[mf], bv[nf], acc[mf][nf]);
            __builtin_amdgcn_s_setprio(0);
            if (hn) {
                asm volatile("s_waitcnt vmcnt(0)" ::: "memory");
                __builtin_amdgcn_s_barrier();
            }
        }
        buf ^= 1;
    }

    // epilogue: seg 0 = Q, seg 1 = K; both [B,H,T,D] bf16
    #pragma unroll
    for (int mf = 0; mf < 8; ++mf) {
        #pragma unroll
        for (int nf = 0; nf < 4; ++nf) {
            #pragma unroll
            for (int r = 0; r < 4; ++r) {
                const int row = m0 + wm*128 + mf*16 + hi*4 + r;   // m
                const int col = n0 + wn*64 + nf*16 + lo;          // n (0..4095)
                const int seg = col >> 11;
                const int c2  = col & (CC-1);
                const int b = row >> 11, t_ = row & (TT-1);
                const int h = c2 >> 7,  d  = c2 & (DD-1);
                __bf16* dst = out + (size_t)seg * MM * CC;
                dst[(size_t)((b*HH + h)*TT + t_)*DD + d] = (__bf16)acc[mf][nf][r];
            }
        }
    }
}

// ---------------------------------------------------------------- GEMM (B^T)
// (R16-verified: ~31us each; ONE barrier + vmcnt(6) per K-tile)
// MODE 1: bf16 [B,H,D,T] (V transposed); MODE 2: fp32 row-major (WO).
template<int MODE>
__global__ __launch_bounds__(512, 2) void gemm_bt(
    const __bf16* __restrict__ A, const __bf16* __restrict__ Wt,
    void* __restrict__ out)
{
    __shared__ __align__(16) __bf16 As[3][256*64];      // 96 KB, 128B rows
    __shared__ __align__(16) __bf16 Bs[3][2][128*32];   // 48 KB, 64B rows, k-sliced

    const int tid = threadIdx.x;
    const int w   = tid >> 6, lane = tid & 63;
    const int wm  = w >> 1,  wn  = w & 1;
    const int lo  = lane & 15, hi = lane >> 4;
    const int xr  = (lo & 7) << 4;
    const int xb2 = ((lo >> 1) & 3) << 4;

    const int bid   = blockIdx.y * gridDim.x + blockIdx.x;
    const int xcd   = bid & 7, loc = bid >> 3;
    const int n0    = (2*xcd + (loc & 1)) * 128;
    const int m0    = (loc >> 1) * 256;

    const int ar   = tid >> 3, as_ = tid & 7;
    const int acol = ((as_ ^ (ar & 7)) << 3);
    const int br   = tid >> 2, bs_ = tid & 3;
    const int bcol = ((bs_ ^ ((br >> 1) & 3)) << 3);

    auto stageA3a = [&](int buf, int kt) {
        #pragma unroll
        for (int j = 0; j < 3; ++j)
            g2lds16(A + (size_t)(m0 + j*64 + ar)*CC + kt*64 + acol,
                    (char*)&As[buf][0] + j*8192 + w*1024);
    };
    auto stageA3b = [&](int buf, int kt) {
        g2lds16(A + (size_t)(m0 + 3*64 + ar)*CC + kt*64 + acol,
                (char*)&As[buf][0] + 3*8192 + w*1024);
        #pragma unroll
        for (int kh = 0; kh < 2; ++kh)
            g2lds16(Wt + (size_t)(n0 + br)*CC + kt*64 + kh*32 + bcol,
                    (char*)&Bs[buf][kh][0] + w*1024);
    };
    auto rdA = [&](bf16x8* af, int buf, int ks) {
        const char* base = (const char*)&As[buf][0];
        #pragma unroll
        for (int mf = 0; mf < 4; ++mf) {
            const int r = wm*64 + mf*16 + lo;
            af[mf] = *(const bf16x8*)(base + r*128 + ((ks*64 + hi*16) ^ xr));
        }
    };
    auto rdB = [&](bf16x8* bv, int buf, int ks) {
        const char* base = (const char*)&Bs[buf][ks][0];
        #pragma unroll
        for (int nf = 0; nf < 4; ++nf) {
            const int n = wn*64 + nf*16 + lo;
            bv[nf] = *(const bf16x8*)(base + n*64 + ((hi*16) ^ xb2));
        }
    };

    f32x4 acc[4][4] = {};

    stageA3a(0, 0); stageA3b(0, 0);
    stageA3a(1, 1); stageA3b(1, 1);
    asm volatile("s_waitcnt vmcnt(6)" ::: "memory");
    __builtin_amdgcn_s_barrier();

    int rb = 0;   // read buffer = t%3
    #pragma unroll 1
    for (int t = 0; t < GNT - 2; ++t) {
        const int sb = (rb == 0) ? 2 : rb - 1;   // (t+2)%3
        {
            bf16x8 af[4], bv[4];
            rdA(af, rb, 0); rdB(bv, rb, 0);
            stageA3a(sb, t + 2);
            __builtin_amdgcn_s_setprio(1);
            #pragma unroll
            for (int mf = 0; mf < 4; ++mf)
                #pragma unroll
                for (int nf = 0; nf < 4; ++nf)
                    acc[mf][nf] = MFMA16(af[mf], bv[nf], acc[mf][nf]);
            __builtin_amdgcn_s_setprio(0);
        }
        {
            bf16x8 af[4], bv[4];
            rdA(af, rb, 1); rdB(bv, rb, 1);
            stageA3b(sb, t + 2);
            __builtin_amdgcn_s_setprio(1);
            #pragma unroll
            for (int mf = 0; mf < 4; ++mf)
                #pragma unroll
                for (int nf = 0; nf < 4; ++nf)
                    acc[mf][nf] = MFMA16(af[mf], bv[nf], acc[mf][nf]);
            __builtin_amdgcn_s_setprio(0);
            asm volatile("s_waitcnt vmcnt(6)" ::: "memory"); // t+1 landed
            __builtin_amdgcn_s_barrier();                    // tile boundary
        }
        rb = (rb == 2) ? 0 : rb + 1;
    }
    {   // peeled t = GNT-2 (no staging)
        bf16x8 af[4], bv[4];
        rdA(af, rb, 0); rdB(bv, rb, 0);
        #pragma unroll
        for (int mf = 0; mf < 4; ++mf)
            #pragma unroll
            for (int nf = 0; nf < 4; ++nf)
                acc[mf][nf] = MFMA16(af[mf], bv[nf], acc[mf][nf]);
        rdA(af, rb, 1); rdB(bv, rb, 1);
        #pragma unroll
        for (int mf = 0; mf < 4; ++mf)
            #pragma unroll
            for (int nf = 0; nf < 4; ++nf)
                acc[mf][nf] = MFMA16(af[mf], bv[nf], acc[mf][nf]);
        asm volatile("s_waitcnt vmcnt(0)" ::: "memory");     // last tile landed
        __builtin_amdgcn_s_barrier();
        rb = (rb == 2) ? 0 : rb + 1;
    }
    {   // peeled t = GNT-1 (compute only)
        bf16x8 af[4], bv[4];
        rdA(af, rb, 0); rdB(bv, rb, 0);
        #pragma unroll
        for (int mf = 0; mf < 4; ++mf)
            #pragma unroll
            for (int nf = 0; nf < 4; ++nf)
                acc[mf][nf] = MFMA16(af[mf], bv[nf], acc[mf][nf]);
        rdA(af, rb, 1); rdB(bv, rb, 1);
        #pragma unroll
        for (int mf = 0; mf < 4; ++mf)
            #pragma unroll
            for (int nf = 0; nf < 4; ++nf)
                acc[mf][nf] = MFMA16(af[mf], bv[nf], acc[mf][nf]);
    }

    #pragma unroll
    for (int mf = 0; mf < 4; ++mf) {
        #pragma unroll
        for (int nf = 0; nf < 4; ++nf) {
            #pragma unroll
            for (int r = 0; r < 4; ++r) {
                const int row = m0 + wm*64 + mf*16 + hi*4 + r;   // m
                const int col = n0 + wn*64 + nf*16 + lo;         // n
                const float v = acc[mf][nf][r];
                if (MODE == 1) {
                    const int b = row >> 11, t = row & (TT-1);
                    const int h = col >> 7,  d = col & (DD-1);
                    ((__bf16*)out)[(size_t)((b*HH + h)*DD + d)*TT + t] = (__bf16)v;
                } else {
                    ((float*)out)[(size_t)row*CC + col] = v;
                }
            }
        }
    }
}

// ---------------------------------------------------------------- attention
// R16 structure + lazy max-reduce: per-lane conservative trigger; exact
// cross-lane max (16 ds_bpermute) + rescale only inside the rare branch.
// grid (NQT/2, B*H) = 512 blocks, 4 waves, causal pairing, bh=lid&31 XCD
// map, KVB=64 dbuf swizzled LDS (72KB, 2 blocks/CU), exp2 softmax,
// ones-MFMA denominator.
__global__ __launch_bounds__(256, 2) void attn_fwd(
    const __bf16* __restrict__ Q, const __bf16* __restrict__ K,
    const __bf16* __restrict__ Vt, __bf16* __restrict__ O)
{
    __shared__ __align__(16) __bf16 Ks[2][64*128];   // 32 KB
    __shared__ __align__(16) __bf16 Vs[2][128*64];   // 32 KB
    __shared__ __align__(16) __bf16 Ps[4][16*64];    //  8 KB

    const int lid   = blockIdx.y * gridDim.x + blockIdx.x;
    const int bh    = lid & 31;            // b*H + h  (bh%8 == XCD id)
    const int pairx = lid >> 5;            // 0..15 causal pair index
    const int tid = threadIdx.x;
    const int w   = tid >> 6, lane = tid & 63;
    const int lo  = lane & 15, hi = lane >> 4;
    const int xr  = (lo & 7) << 4;         // read-side swizzle XOR (row bits)

    const int krow_l  = lane >> 4;                        // 0..3
    const int kcol_sw = ((lane & 15) << 4);               // 0..240 (bytes)
    const int vrow_l  = lane >> 3;                        // 0..7
    const int vcol_sw = (((lane & 7) ^ (lane >> 3)) << 3); // pre-swz elem off

    const size_t kbase = (size_t)bh * TT * DD;
    const size_t vbase = (size_t)bh * DD * TT;
    const int b = bh >> 4, h = bh & 15;
    const float SC = 0.12754613142f;   // D^-0.5 * log2(e)

    bf16x8 vones;
    #pragma unroll
    for (int i = 0; i < 8; ++i) vones[i] = (__bf16)1.0f;

    auto stage = [&](int buf, int kv0) {
        #pragma unroll
        for (int i = 0; i < 4; ++i) {
            const int c = 4*w + i;
            {   // K: row = 4c + krow_l; src col byte = kcol_sw ^ ((row&7)<<4)
                const int row = 4*c + krow_l;
                const int sw  = (kcol_sw ^ ((row & 7) << 4)) >> 1;
                g2lds16(K + kbase + (size_t)(kv0 + row)*DD + sw,
                        &Ks[buf][0] + c*512);
            }
            {   // Vt: row(d) = 8c + vrow_l
                const int row = 8*c + vrow_l;
                g2lds16(Vt + vbase + (size_t)row*TT + kv0 + vcol_sw,
                        &Vs[buf][0] + c*512);
            }
        }
    };

    #pragma unroll 1
    for (int half = 0; half < 2; ++half) {
        const int qt = half ? pairx : (NQT - 1 - pairx);
        const int q0 = qt * 64;

        const __bf16* Qbase = Q + (kbase + (size_t)(q0 + w*16 + lo) * DD);
        bf16x8 qf[4];
        #pragma unroll
        for (int kc = 0; kc < 4; ++kc)
            qf[kc] = *(const bf16x8*)(Qbase + kc*32 + hi*8);

        float mrow[4];
        #pragma unroll
        for (int r = 0; r < 4; ++r) mrow[r] = -1e30f;
        f32x4 oacc[8] = {};   // out rows q=4*hi+r, cols d = dc*16+lo
        f32x4 sacc = {};      // row-sum accumulator (denominator)

        const int qg_base = q0 + w*16 + hi*4;  // + r
        const int ntiles  = qt + 1;            // causal: kv tiles 0..qt

        stage(0, 0);
        __syncthreads();
        int cur = 0;

        for (int t = 0; t < ntiles; ++t) {
            const int kv0 = t*64;
            if (t + 1 < ntiles) stage(cur ^ 1, (t+1)*64);

            const char* Kb = (const char*)&Ks[cur][0];
            const char* Vb = (const char*)&Vs[cur][0];

            // S = Q K^T : lane holds S[q=4hi+r][kv=st*16+lo]
            f32x4 s[4];
            __builtin_amdgcn_s_setprio(1);
            #pragma unroll
            for (int st = 0; st < 4; ++st) {
                f32x4 a = {};
                #pragma unroll
                for (int kc = 0; kc < 4; ++kc) {
                    const bf16x8 kf = *(const bf16x8*)(
                        Kb + (st*16 + lo)*256 + ((kc*64 + hi*16) ^ xr));
                    a = MFMA16(qf[kc], kf, a);
                }
                s[st] = a;
            }
            __builtin_amdgcn_s_setprio(0);

            // scale into log2 domain + (diagonal-only) causal mask
            // + LANE-LOCAL max (no cross-lane reduce in the common path)
            float lmax[4];
            const bool diag = (t == ntiles - 1);
            #pragma unroll
            for (int r = 0; r < 4; ++r) {
                const int qg = qg_base + r;
                float mx = -1e30f;
                #pragma unroll
                for (int st = 0; st < 4; ++st) {
                    float v = s[st][r] * SC;
                    if (diag) {
                        const int kvg = kv0 + st*16 + lo;
                        v = (kvg > qg) ? -1e30f : v;
                    }
                    s[st][r] = v;
                    mx = fmaxf(mx, v);
                }
                lmax[r] = mx;
            }

            // lazy defer-max: conservative lane-local trigger. If no lane's
            // local max exceeds mrow+THR, the true row max doesn't either.
            bool need = false;
            #pragma unroll
            for (int r = 0; r < 4; ++r)
                need = need || (lmax[r] > mrow[r] + 11.5f);
            if (__any(need)) {
                // exact cross-lane row max (only on trigger; wave-uniform)
                float pmax[4], rsc[4];
                #pragma unroll
                for (int r = 0; r < 4; ++r) {
                    float mx = lmax[r];
                    #pragma unroll
                    for (int msk = 1; msk < 16; msk <<= 1)
                        mx = fmaxf(mx, __shfl_xor(mx, msk, 64));
                    pmax[r] = mx;
                }
                #pragma unroll
                for (int r = 0; r < 4; ++r) {
                    const float mnew = fmaxf(mrow[r], pmax[r]);
                    rsc[r]  = __builtin_amdgcn_exp2f(mrow[r] - mnew);
                    mrow[r] = mnew;
                    sacc[r] *= rsc[r];
                }
                #pragma unroll
                for (int dc = 0; dc < 8; ++dc)
                    #pragma unroll
                    for (int r = 0; r < 4; ++r)
                        oacc[dc][r] *= rsc[r];
            }

            // P = exp2(s - m) (bounded by 2^THR); denominator via ones-MFMA
            #pragma unroll
            for (int r = 0; r < 4; ++r)
                #pragma unroll
                for (int st = 0; st < 4; ++st)
                    s[st][r] = __builtin_amdgcn_exp2f(s[st][r] - mrow[r]);

            // P -> per-wave swizzled LDS (wave-private: no barrier)
            char* Pw = (char*)&Ps[w][0];
            #pragma unroll
            for (int st = 0; st < 4; ++st)
                #pragma unroll
                for (int r = 0; r < 4; ++r) {
                    const int row = hi*4 + r;
                    *(__bf16*)(Pw + row*128 + (((st*16 + lo)*2) ^ ((row & 7) << 4)))
                        = (__bf16)s[st][r];
                }

            // PV: out[q][d] += P[q][kv] V[kv][d];  sacc += P row-sums
            __builtin_amdgcn_s_setprio(1);
            #pragma unroll
            for (int kc2 = 0; kc2 < 2; ++kc2) {
                const bf16x8 pf = *(const bf16x8*)(
                    Pw + lo*128 + ((kc2*64 + hi*16) ^ xr));
                #pragma unroll
                for (int dc = 0; dc < 8; ++dc) {
                    const bf16x8 vf = *(const bf16x8*)(
                        Vb + (dc*16 + lo)*128 + ((kc2*64 + hi*16) ^ xr));
                    oacc[dc] = MFMA16(pf, vf, oacc[dc]);
                }
                sacc = MFMA16(pf, vones, sacc);   // denominator (free pipe)
            }
            __builtin_amdgcn_s_setprio(0);

            __syncthreads();   // drains prefetch vmcnt + protects buffer swap
            cur ^= 1;
        }

        // epilogue: normalize by MFMA-accumulated row sums, write bf16
        #pragma unroll
        for (int r = 0; r < 4; ++r) {
            const float inv = 1.f / sacc[r];
            const int qg = qg_base + r;
            #pragma unroll
            for (int dc = 0; dc < 8; ++dc) {
                const int d = dc*16 + lo;
                O[(size_t)(b*TT + qg)*CC + h*DD + d] = (__bf16)(oacc[dc][r] * inv);
            }
        }
    }
}

// ---------------------------------------------------------------- launch
extern "C" void kernel_launch(void* const* d_in, const int* in_sizes, int n_in,
                              void* d_out, int out_size, void* d_ws, size_t ws_size,
                              hipStream_t stream) {
    const float* x  = (const float*)d_in[0];
    // d_in[1] = mask (causal, implemented analytically)
    const float* wq = (const float*)d_in[2];
    const float* wk = (const float*)d_in[3];
    const float* wv = (const float*)d_in[4];
    const float* wo = (const float*)d_in[5];

    char* p = (char*)d_ws;
    __bf16* xb  = (__bf16*)p; p += (size_t)MM*CC*2;   // also reused as attn-out
    __bf16* wqb = (__bf16*)p; p += (size_t)CC*CC*2;   // wq,wk contiguous (fused N=4096)
    __bf16* wkb = (__bf16*)p; p += (size_t)CC*CC*2;
    __bf16* wvb = (__bf16*)p; p += (size_t)CC*CC*2;
    __bf16* wob = (__bf16*)p; p += (size_t)CC*CC*2;
    __bf16* Qb  = (__bf16*)p; p += (size_t)MM*CC*2;   // Q,K contiguous (gemm_qk out)
    __bf16* Kb  = (__bf16*)p; p += (size_t)MM*CC*2;
    __bf16* Vtb = (__bf16*)p; p += (size_t)MM*CC*2;
    __bf16* AOb = xb;  // x no longer needed after QKV GEMMs (stream-ordered)
    (void)wkb;

    cvt_all<<<24576, 256, 0, stream>>>(x, wq, wk, wv, wo, xb);

    gemm_qk<<<dim3(16, 16), 512, 0, stream>>>(xb, wqb, Qb);
    gemm_bt<1><<<dim3(16, 16), 512, 0, stream>>>(xb, wvb, Vtb);

    attn_fwd<<<dim3(NQT/2, BB*HH), 256, 0, stream>>>(Qb, Kb, Vtb, AOb);

    gemm_bt<2><<<dim3(16, 16), 512, 0, stream>>>(AOb, wob, (void*)d_out);
}

// Round 20
// 208.165 us; speedup vs baseline: 1.2022x; 1.0213x over previous
//
#include <hip/hip_runtime.h>
#include <hip/hip_bf16.h>
#include <string.h>

// Causal attention block: out = softmax(mask(QK^T/sqrt(D))) V projections.
// B=2, T=2048, C=2048, H=16, D=128. fp32 I/O, bf16 MFMA compute internally.
//
// Pipeline:
//   1. cvt_all: x + 4 weights f32->bf16 in ONE launch
//   2. gemm_qk: fused Q+K = x@[wq;wk].T (N=4096, 256x256 tile) -> [B,H,T,D]x2
//      gemm_bt<1>: V = x@wv.T -> [B,H,D,T]
//   3. attn_fwd: swapped-operand QK (S^T = MFMA(K,Q), same fragments):
//        softmax fully per-lane-scalar (q = lane&15), P-write = 4x b64
//        (vs 16x b16), lazy max-reduce (2 shfls, rare branch only),
//        ones-MFMA denominator, defer-max, bh->XCD map, causal pairing.
//   4. gemm_bt<2>: out = attn@wo.T -> fp32 d_out

#define BB 2
#define TT 2048
#define CC 2048
#define HH 16
#define DD 128
#define MM (BB*TT)   // 4096
#define NQT (TT/64)  // 32 q-tiles (64 rows each)
#define GNT (CC/64)  // 32 K-tiles in GEMM

typedef __bf16 bf16x8 __attribute__((ext_vector_type(8)));
typedef __bf16 bf16x4 __attribute__((ext_vector_type(4)));
typedef float  f32x4  __attribute__((ext_vector_type(4)));

#define MFMA16(a, b, c) __builtin_amdgcn_mfma_f32_16x16x32_bf16((a), (b), (c), 0, 0, 0)

__device__ __forceinline__ void g2lds16(const void* g, void* l) {
    __builtin_amdgcn_global_load_lds(
        (const __attribute__((address_space(1))) void*)g,
        (__attribute__((address_space(3))) void*)l,
        16, 0, 0);
}

__device__ __forceinline__ unsigned pack_bf16x2(float a, float b) {
    __bf16 ba = (__bf16)a, bb = (__bf16)b;
    unsigned short ua, ub;
    memcpy(&ua, &ba, 2); memcpy(&ub, &bb, 2);
    return (unsigned)ua | ((unsigned)ub << 16);
}

// ---------------------------------------------------------------- convert
__global__ __launch_bounds__(256) void cvt_all(
    const float* __restrict__ x,  const float* __restrict__ wq,
    const float* __restrict__ wk, const float* __restrict__ wv,
    const float* __restrict__ wo, __bf16* __restrict__ out_base)
{
    const int idx = blockIdx.x * 256 + threadIdx.x;   // < 6291456
    const float* in; int off;
    if (idx < (1 << 21)) { in = x; off = idx; }
    else {
        const int r = idx - (1 << 21);
        const int k = r >> 20;
        in  = (k == 0) ? wq : (k == 1) ? wk : (k == 2) ? wv : wo;
        off = r & ((1 << 20) - 1);
    }
    const float4 v = ((const float4*)in)[off];
    bf16x4 o;
    o.x = (__bf16)v.x; o.y = (__bf16)v.y;
    o.z = (__bf16)v.z; o.w = (__bf16)v.w;
    ((bf16x4*)out_base)[idx] = o;
}

// ---------------------------------------------------------------- gemm_qk
// Fused Q+K: N=4096 (wq;wk), BM=BN=256, BK=64; grid (16,16)=256=1/CU.
// 8 waves 2Mx4N -> wave tile 128x64. LDS double-buffer 128KB.
__global__ __launch_bounds__(512, 2) void gemm_qk(
    const __bf16* __restrict__ A, const __bf16* __restrict__ Wt,
    __bf16* __restrict__ out)
{
    __shared__ __align__(16) __bf16 As[2][256*64];      // 64 KB, 128B rows
    __shared__ __align__(16) __bf16 Bs[2][2][256*32];   // 64 KB, 64B rows, k-sliced

    const int tid = threadIdx.x;
    const int w   = tid >> 6, lane = tid & 63;
    const int wm  = w >> 2,  wn  = w & 3;         // 2M x 4N
    const int lo  = lane & 15, hi = lane >> 4;
    const int xr  = (lo & 7) << 4;
    const int xb2 = ((lo >> 1) & 3) << 4;

    const int bid = blockIdx.y * gridDim.x + blockIdx.x;
    const int xcd = bid & 7, loc = bid >> 3;
    const int n0  = (2*xcd + (loc & 1)) * 256;
    const int m0  = (loc >> 1) * 256;

    const int ar   = tid >> 3, as_ = tid & 7;
    const int acol = ((as_ ^ (ar & 7)) << 3);
    const int brr  = tid >> 2, bs_ = tid & 3;
    const int bcol = ((bs_ ^ ((brr >> 1) & 3)) << 3);

    auto stageA = [&](int buf, int kt) {
        #pragma unroll
        for (int j = 0; j < 4; ++j)
            g2lds16(A + (size_t)(m0 + j*64 + ar)*CC + kt*64 + acol,
                    (char*)&As[buf][0] + j*8192 + w*1024);
    };
    auto stageB = [&](int buf, int kt) {
        #pragma unroll
        for (int ks = 0; ks < 2; ++ks)
            #pragma unroll
            for (int jb = 0; jb < 2; ++jb)
                g2lds16(Wt + (size_t)(n0 + jb*128 + brr)*CC + kt*64 + ks*32 + bcol,
                        (char*)&Bs[buf][ks][0] + jb*8192 + w*1024);
    };
    auto rdA = [&](bf16x8* af, int buf, int ks) {
        const char* base = (const char*)&As[buf][0];
        #pragma unroll
        for (int mf = 0; mf < 8; ++mf) {
            const int r = wm*128 + mf*16 + lo;
            af[mf] = *(const bf16x8*)(base + r*128 + ((ks*64 + hi*16) ^ xr));
        }
    };
    auto rdB = [&](bf16x8* bv, int buf, int ks) {
        const char* base = (const char*)&Bs[buf][ks][0];
        #pragma unroll
        for (int nf = 0; nf < 4; ++nf) {
            const int n = wn*64 + nf*16 + lo;
            bv[nf] = *(const bf16x8*)(base + n*64 + ((hi*16) ^ xb2));
        }
    };

    f32x4 acc[8][4] = {};

    stageA(0, 0); stageB(0, 0);
    asm volatile("s_waitcnt vmcnt(0)" ::: "memory");
    __builtin_amdgcn_s_barrier();

    int buf = 0;
    #pragma unroll 1
    for (int t = 0; t < GNT; ++t) {
        const bool hn = (t + 1 < GNT);
        {
            bf16x8 af[8], bv[4];
            rdA(af, buf, 0); rdB(bv, buf, 0);
            if (hn) stageA(buf ^ 1, t + 1);
            __builtin_amdgcn_s_setprio(1);
            #pragma unroll
            for (int mf = 0; mf < 8; ++mf)
                #pragma unroll
                for (int nf = 0; nf < 4; ++nf)
                    acc[mf][nf] = MFMA16(af[mf], bv[nf], acc[mf][nf]);
            __builtin_amdgcn_s_setprio(0);
        }
        {
            bf16x8 af[8], bv[4];
            rdA(af, buf, 1); rdB(bv, buf, 1);
            if (hn) stageB(buf ^ 1, t + 1);
            __builtin_amdgcn_s_setprio(1);
            #pragma unroll
            for (int mf = 0; mf < 8; ++mf)
                #pragma unroll
                for (int nf = 0; nf < 4; ++nf)
                    acc[mf][nf] = MFMA16(af[mf], bv[nf], acc[mf][nf]);
            __builtin_amdgcn_s_setprio(0);
            if (hn) {
                asm volatile("s_waitcnt vmcnt(0)" ::: "memory");
                __builtin_amdgcn_s_barrier();
            }
        }
        buf ^= 1;
    }

    // epilogue: seg 0 = Q, seg 1 = K; both [B,H,T,D] bf16
    #pragma unroll
    for (int mf = 0; mf < 8; ++mf) {
        #pragma unroll
        for (int nf = 0; nf < 4; ++nf) {
            #pragma unroll
            for (int r = 0; r < 4; ++r) {
                const int row = m0 + wm*128 + mf*16 + hi*4 + r;   // m
                const int col = n0 + wn*64 + nf*16 + lo;          // n (0..4095)
                const int seg = col >> 11;
                const int c2  = col & (CC-1);
                const int b = row >> 11, t_ = row & (TT-1);
                const int h = c2 >> 7,  d  = c2 & (DD-1);
                __bf16* dst = out + (size_t)seg * MM * CC;
                dst[(size_t)((b*HH + h)*TT + t_)*DD + d] = (__bf16)acc[mf][nf][r];
            }
        }
    }
}

// ---------------------------------------------------------------- GEMM (B^T)
// (R16-verified: ~31us each; ONE barrier + vmcnt(6) per K-tile)
// MODE 1: bf16 [B,H,D,T] (V transposed); MODE 2: fp32 row-major (WO).
template<int MODE>
__global__ __launch_bounds__(512, 2) void gemm_bt(
    const __bf16* __restrict__ A, const __bf16* __restrict__ Wt,
    void* __restrict__ out)
{
    __shared__ __align__(16) __bf16 As[3][256*64];      // 96 KB, 128B rows
    __shared__ __align__(16) __bf16 Bs[3][2][128*32];   // 48 KB, 64B rows, k-sliced

    const int tid = threadIdx.x;
    const int w   = tid >> 6, lane = tid & 63;
    const int wm  = w >> 1,  wn  = w & 1;
    const int lo  = lane & 15, hi = lane >> 4;
    const int xr  = (lo & 7) << 4;
    const int xb2 = ((lo >> 1) & 3) << 4;

    const int bid   = blockIdx.y * gridDim.x + blockIdx.x;
    const int xcd   = bid & 7, loc = bid >> 3;
    const int n0    = (2*xcd + (loc & 1)) * 128;
    const int m0    = (loc >> 1) * 256;

    const int ar   = tid >> 3, as_ = tid & 7;
    const int acol = ((as_ ^ (ar & 7)) << 3);
    const int br   = tid >> 2, bs_ = tid & 3;
    const int bcol = ((bs_ ^ ((br >> 1) & 3)) << 3);

    auto stageA3a = [&](int buf, int kt) {
        #pragma unroll
        for (int j = 0; j < 3; ++j)
            g2lds16(A + (size_t)(m0 + j*64 + ar)*CC + kt*64 + acol,
                    (char*)&As[buf][0] + j*8192 + w*1024);
    };
    auto stageA3b = [&](int buf, int kt) {
        g2lds16(A + (size_t)(m0 + 3*64 + ar)*CC + kt*64 + acol,
                (char*)&As[buf][0] + 3*8192 + w*1024);
        #pragma unroll
        for (int kh = 0; kh < 2; ++kh)
            g2lds16(Wt + (size_t)(n0 + br)*CC + kt*64 + kh*32 + bcol,
                    (char*)&Bs[buf][kh][0] + w*1024);
    };
    auto rdA = [&](bf16x8* af, int buf, int ks) {
        const char* base = (const char*)&As[buf][0];
        #pragma unroll
        for (int mf = 0; mf < 4; ++mf) {
            const int r = wm*64 + mf*16 + lo;
            af[mf] = *(const bf16x8*)(base + r*128 + ((ks*64 + hi*16) ^ xr));
        }
    };
    auto rdB = [&](bf16x8* bv, int buf, int ks) {
        const char* base = (const char*)&Bs[buf][ks][0];
        #pragma unroll
        for (int nf = 0; nf < 4; ++nf) {
            const int n = wn*64 + nf*16 + lo;
            bv[nf] = *(const bf16x8*)(base + n*64 + ((hi*16) ^ xb2));
        }
    };

    f32x4 acc[4][4] = {};

    stageA3a(0, 0); stageA3b(0, 0);
    stageA3a(1, 1); stageA3b(1, 1);
    asm volatile("s_waitcnt vmcnt(6)" ::: "memory");
    __builtin_amdgcn_s_barrier();

    int rb = 0;   // read buffer = t%3
    #pragma unroll 1
    for (int t = 0; t < GNT - 2; ++t) {
        const int sb = (rb == 0) ? 2 : rb - 1;   // (t+2)%3
        {
            bf16x8 af[4], bv[4];
            rdA(af, rb, 0); rdB(bv, rb, 0);
            stageA3a(sb, t + 2);
            __builtin_amdgcn_s_setprio(1);
            #pragma unroll
            for (int mf = 0; mf < 4; ++mf)
                #pragma unroll
                for (int nf = 0; nf < 4; ++nf)
                    acc[mf][nf] = MFMA16(af[mf], bv[nf], acc[mf][nf]);
            __builtin_amdgcn_s_setprio(0);
        }
        {
            bf16x8 af[4], bv[4];
            rdA(af, rb, 1); rdB(bv, rb, 1);
            stageA3b(sb, t + 2);
            __builtin_amdgcn_s_setprio(1);
            #pragma unroll
            for (int mf = 0; mf < 4; ++mf)
                #pragma unroll
                for (int nf = 0; nf < 4; ++nf)
                    acc[mf][nf] = MFMA16(af[mf], bv[nf], acc[mf][nf]);
            __builtin_amdgcn_s_setprio(0);
            asm volatile("s_waitcnt vmcnt(6)" ::: "memory"); // t+1 landed
            __builtin_amdgcn_s_barrier();                    // tile boundary
        }
        rb = (rb == 2) ? 0 : rb + 1;
    }
    {   // peeled t = GNT-2 (no staging)
        bf16x8 af[4], bv[4];
        rdA(af, rb, 0); rdB(bv, rb, 0);
        #pragma unroll
        for (int mf = 0; mf < 4; ++mf)
            #pragma unroll
            for (int nf = 0; nf < 4; ++nf)
                acc[mf][nf] = MFMA16(af[mf], bv[nf], acc[mf][nf]);
        rdA(af, rb, 1); rdB(bv, rb, 1);
        #pragma unroll
        for (int mf = 0; mf < 4; ++mf)
            #pragma unroll
            for (int nf = 0; nf < 4; ++nf)
                acc[mf][nf] = MFMA16(af[mf], bv[nf], acc[mf][nf]);
        asm volatile("s_waitcnt vmcnt(0)" ::: "memory");     // last tile landed
        __builtin_amdgcn_s_barrier();
        rb = (rb == 2) ? 0 : rb + 1;
    }
    {   // peeled t = GNT-1 (compute only)
        bf16x8 af[4], bv[4];
        rdA(af, rb, 0); rdB(bv, rb, 0);
        #pragma unroll
        for (int mf = 0; mf < 4; ++mf)
            #pragma unroll
            for (int nf = 0; nf < 4; ++nf)
                acc[mf][nf] = MFMA16(af[mf], bv[nf], acc[mf][nf]);
        rdA(af, rb, 1); rdB(bv, rb, 1);
        #pragma unroll
        for (int mf = 0; mf < 4; ++mf)
            #pragma unroll
            for (int nf = 0; nf < 4; ++nf)
                acc[mf][nf] = MFMA16(af[mf], bv[nf], acc[mf][nf]);
    }

    #pragma unroll
    for (int mf = 0; mf < 4; ++mf) {
        #pragma unroll
        for (int nf = 0; nf < 4; ++nf) {
            #pragma unroll
            for (int r = 0; r < 4; ++r) {
                const int row = m0 + wm*64 + mf*16 + hi*4 + r;   // m
                const int col = n0 + wn*64 + nf*16 + lo;         // n
                const float v = acc[mf][nf][r];
                if (MODE == 1) {
                    const int b = row >> 11, t = row & (TT-1);
                    const int h = col >> 7,  d = col & (DD-1);
                    ((__bf16*)out)[(size_t)((b*HH + h)*DD + d)*TT + t] = (__bf16)v;
                } else {
                    ((float*)out)[(size_t)row*CC + col] = v;
                }
            }
        }
    }
}

// ---------------------------------------------------------------- attention
// Swapped-operand QK: S^T = MFMA(kf, qf) with the SAME LDS fragments (A/B
// frag layouts coincide). Lane holds S[kv=st*16+4hi+r][q=lo] -> softmax is
// per-lane scalar (mrow/lmax/rsc single values); P-write = 4x ds_write_b64
// per tile (r-quads kv-contiguous). PV unchanged (reads P as A-frag);
// defer-max rescale remaps per-lane rsc to output rows with 4 shfls (rare).
// grid (NQT/2, B*H) = 512 blocks, causal pairing, bh=lid&31 XCD map,
// KVB=64 dbuf swizzled LDS (72KB, 2 blocks/CU), ones-MFMA denominator.
__global__ __launch_bounds__(256, 2) void attn_fwd(
    const __bf16* __restrict__ Q, const __bf16* __restrict__ K,
    const __bf16* __restrict__ Vt, __bf16* __restrict__ O)
{
    __shared__ __align__(16) __bf16 Ks[2][64*128];   // 32 KB
    __shared__ __align__(16) __bf16 Vs[2][128*64];   // 32 KB
    __shared__ __align__(16) __bf16 Ps[4][16*64];    //  8 KB

    const int lid   = blockIdx.y * gridDim.x + blockIdx.x;
    const int bh    = lid & 31;            // b*H + h  (bh%8 == XCD id)
    const int pairx = lid >> 5;            // 0..15 causal pair index
    const int tid = threadIdx.x;
    const int w   = tid >> 6, lane = tid & 63;
    const int lo  = lane & 15, hi = lane >> 4;
    const int xr  = (lo & 7) << 4;         // swizzle XOR (row bits)

    const int krow_l  = lane >> 4;                        // 0..3
    const int kcol_sw = ((lane & 15) << 4);               // 0..240 (bytes)
    const int vrow_l  = lane >> 3;                        // 0..7
    const int vcol_sw = (((lane & 7) ^ (lane >> 3)) << 3); // pre-swz elem off

    const size_t kbase = (size_t)bh * TT * DD;
    const size_t vbase = (size_t)bh * DD * TT;
    const int b = bh >> 4, h = bh & 15;
    const float SC = 0.12754613142f;   // D^-0.5 * log2(e)

    bf16x8 vones;
    #pragma unroll
    for (int i = 0; i < 8; ++i) vones[i] = (__bf16)1.0f;

    auto stage = [&](int buf, int kv0) {
        #pragma unroll
        for (int i = 0; i < 4; ++i) {
            const int c = 4*w + i;
            {   // K: row = 4c + krow_l; src col byte = kcol_sw ^ ((row&7)<<4)
                const int row = 4*c + krow_l;
                const int sw  = (kcol_sw ^ ((row & 7) << 4)) >> 1;
                g2lds16(K + kbase + (size_t)(kv0 + row)*DD + sw,
                        &Ks[buf][0] + c*512);
            }
            {   // Vt: row(d) = 8c + vrow_l
                const int row = 8*c + vrow_l;
                g2lds16(Vt + vbase + (size_t)row*TT + kv0 + vcol_sw,
                        &Vs[buf][0] + c*512);
            }
        }
    };

    #pragma unroll 1
    for (int half = 0; half < 2; ++half) {
        const int qt = half ? pairx : (NQT - 1 - pairx);
        const int q0 = qt * 64;

        const __bf16* Qbase = Q + (kbase + (size_t)(q0 + w*16 + lo) * DD);
        bf16x8 qf[4];
        #pragma unroll
        for (int kc = 0; kc < 4; ++kc)
            qf[kc] = *(const bf16x8*)(Qbase + kc*32 + hi*8);

        float mrow = -1e30f;            // per-lane: q = lo (swapped layout)
        f32x4 oacc[8] = {};             // out rows q=4*hi+r, cols d=dc*16+lo
        f32x4 sacc = {};                // denominator, rows q=4*hi+r

        const int qg_lane = q0 + w*16 + lo;        // this lane's q (S^T col)
        const int qg_base = q0 + w*16 + hi*4;      // output rows (+r)
        const int ntiles  = qt + 1;                // causal: kv tiles 0..qt

        stage(0, 0);
        __syncthreads();
        int cur = 0;

        for (int t = 0; t < ntiles; ++t) {
            const int kv0 = t*64;
            if (t + 1 < ntiles) stage(cur ^ 1, (t+1)*64);

            const char* Kb = (const char*)&Ks[cur][0];
            const char* Vb = (const char*)&Vs[cur][0];

            // S^T = K Q^T : lane holds S[kv=st*16+4hi+r][q=lo]
            f32x4 s[4];
            __builtin_amdgcn_s_setprio(1);
            #pragma unroll
            for (int st = 0; st < 4; ++st) {
                f32x4 a = {};
                #pragma unroll
                for (int kc = 0; kc < 4; ++kc) {
                    const bf16x8 kf = *(const bf16x8*)(
                        Kb + (st*16 + lo)*256 + ((kc*64 + hi*16) ^ xr));
                    a = MFMA16(kf, qf[kc], a);     // swapped operands
                }
                s[st] = a;
            }
            __builtin_amdgcn_s_setprio(0);

            // scale + (diagonal-only) causal mask + per-lane max (scalar)
            float lmax = -1e30f;
            const bool diag = (t == ntiles - 1);
            #pragma unroll
            for (int st = 0; st < 4; ++st) {
                #pragma unroll
                for (int r = 0; r < 4; ++r) {
                    float v = s[st][r] * SC;
                    if (diag) {
                        const int kvg = kv0 + st*16 + hi*4 + r;
                        v = (kvg > qg_lane) ? -1e30f : v;
                    }
                    s[st][r] = v;
                    lmax = fmaxf(lmax, v);
                }
            }

            // lazy defer-max (rare): exact max over the 4 hi-lanes sharing q
            if (__any(lmax > mrow + 11.5f)) {
                float mx = lmax;
                mx = fmaxf(mx, __shfl_xor(mx, 16, 64));
                mx = fmaxf(mx, __shfl_xor(mx, 32, 64));
                const float mnew = fmaxf(mrow, mx);
                const float rsc  = __builtin_amdgcn_exp2f(mrow - mnew);
                mrow = mnew;
                // remap per-lane rsc (q=lo) to output rows q=4*hi+r
                float rscO[4];
                #pragma unroll
                for (int r = 0; r < 4; ++r)
                    rscO[r] = __shfl(rsc, (lane & 48) | (hi*4 + r), 64);
                #pragma unroll
                for (int r = 0; r < 4; ++r) sacc[r] *= rscO[r];
                #pragma unroll
                for (int dc = 0; dc < 8; ++dc)
                    #pragma unroll
                    for (int r = 0; r < 4; ++r)
                        oacc[dc][r] *= rscO[r];
            }

            // P = exp2(s - mrow) (scalar mrow; bounded by 2^THR)
            #pragma unroll
            for (int st = 0; st < 4; ++st)
                #pragma unroll
                for (int r = 0; r < 4; ++r)
                    s[st][r] = __builtin_amdgcn_exp2f(s[st][r] - mrow);

            // P -> per-wave LDS as [q=lo][kv], 4x b64 (r-quad kv-contiguous)
            char* Pw = (char*)&Ps[w][0];
            #pragma unroll
            for (int st = 0; st < 4; ++st) {
                uint2 dw;
                dw.x = pack_bf16x2(s[st][0], s[st][1]);
                dw.y = pack_bf16x2(s[st][2], s[st][3]);
                *(uint2*)(Pw + lo*128 + ((st*32 + hi*8) ^ xr)) = dw;
            }

            // PV: out[q][d] += P[q][kv] V[kv][d];  sacc += P row-sums
            __builtin_amdgcn_s_setprio(1);
            #pragma unroll
            for (int kc2 = 0; kc2 < 2; ++kc2) {
                const bf16x8 pf = *(const bf16x8*)(
                    Pw + lo*128 + ((kc2*64 + hi*16) ^ xr));
                #pragma unroll
                for (int dc = 0; dc < 8; ++dc) {
                    const bf16x8 vf = *(const bf16x8*)(
                        Vb + (dc*16 + lo)*128 + ((kc2*64 + hi*16) ^ xr));
                    oacc[dc] = MFMA16(pf, vf, oacc[dc]);
                }
                sacc = MFMA16(pf, vones, sacc);   // denominator (free pipe)
            }
            __builtin_amdgcn_s_setprio(0);

            __syncthreads();   // drains prefetch vmcnt + protects buffer swap
            cur ^= 1;
        }

        // epilogue: normalize by MFMA-accumulated row sums, write bf16
        #pragma unroll
        for (int r = 0; r < 4; ++r) {
            const float inv = 1.f / sacc[r];
            const int qg = qg_base + r;
            #pragma unroll
            for (int dc = 0; dc < 8; ++dc) {
                const int d = dc*16 + lo;
                O[(size_t)(b*TT + qg)*CC + h*DD + d] = (__bf16)(oacc[dc][r] * inv);
            }
        }
    }
}

// ---------------------------------------------------------------- launch
extern "C" void kernel_launch(void* const* d_in, const int* in_sizes, int n_in,
                              void* d_out, int out_size, void* d_ws, size_t ws_size,
                              hipStream_t stream) {
    const float* x  = (const float*)d_in[0];
    // d_in[1] = mask (causal, implemented analytically)
    const float* wq = (const float*)d_in[2];
    const float* wk = (const float*)d_in[3];
    const float* wv = (const float*)d_in[4];
    const float* wo = (const float*)d_in[5];

    char* p = (char*)d_ws;
    __bf16* xb  = (__bf16*)p; p += (size_t)MM*CC*2;   // also reused as attn-out
    __bf16* wqb = (__bf16*)p; p += (size_t)CC*CC*2;   // wq,wk contiguous (fused N=4096)
    __bf16* wkb = (__bf16*)p; p += (size_t)CC*CC*2;
    __bf16* wvb = (__bf16*)p; p += (size_t)CC*CC*2;
    __bf16* wob = (__bf16*)p; p += (size_t)CC*CC*2;
    __bf16* Qb  = (__bf16*)p; p += (size_t)MM*CC*2;   // Q,K contiguous (gemm_qk out)
    __bf16* Kb  = (__bf16*)p; p += (size_t)MM*CC*2;
    __bf16* Vtb = (__bf16*)p; p += (size_t)MM*CC*2;
    __bf16* AOb = xb;  // x no longer needed after QKV GEMMs (stream-ordered)
    (void)wkb;

    cvt_all<<<24576, 256, 0, stream>>>(x, wq, wk, wv, wo, xb);

    gemm_qk<<<dim3(16, 16), 512, 0, stream>>>(xb, wqb, Qb);
    gemm_bt<1><<<dim3(16, 16), 512, 0, stream>>>(xb, wvb, Vtb);

    attn_fwd<<<dim3(NQT/2, BB*HH), 256, 0, stream>>>(Qb, Kb, Vtb, AOb);

    gemm_bt<2><<<dim3(16, 16), 512, 0, stream>>>(AOb, wob, (void*)d_out);
}